// Round 3
// baseline (8001.420 us; speedup 1.0000x reference)
//
#include <hip/hip_runtime.h>
#include <hip/hip_fp16.h>
#include <cstdint>

typedef _Float16 f16;
typedef _Float16 f16x8 __attribute__((ext_vector_type(8)));
typedef float f32x4 __attribute__((ext_vector_type(4)));

#define BATCH 128

// ---------------------------------------------------------------- conv + relu
template<int CI>
__global__ void conv3x3s2_relu(const float* __restrict__ in, const float* __restrict__ w,
                               const float* __restrict__ bias, float* __restrict__ out,
                               int CO, int H, int W) {
  int OH = H >> 1, OW = W >> 1;
  int total = BATCH * CO * OH * OW;
  int idx = blockIdx.x * blockDim.x + threadIdx.x;
  if (idx >= total) return;
  int ox = idx % OW; int t = idx / OW;
  int oy = t % OH; t /= OH;
  int co = t % CO; int b = t / CO;
  float acc = bias[co];
  const float* wp = w + (size_t)co * CI * 9;
  const float* ip = in + (size_t)b * CI * H * W;
  int iy0 = oy * 2 - 1, ix0 = ox * 2 - 1;
  for (int ci = 0; ci < CI; ++ci) {
    const float* ipc = ip + (size_t)ci * H * W;
    const float* wpc = wp + ci * 9;
    #pragma unroll
    for (int ky = 0; ky < 3; ++ky) {
      int iy = iy0 + ky;
      if ((unsigned)iy >= (unsigned)H) continue;
      #pragma unroll
      for (int kx = 0; kx < 3; ++kx) {
        int ix = ix0 + kx;
        if ((unsigned)ix >= (unsigned)W) continue;
        acc += ipc[iy * W + ix] * wpc[ky * 3 + kx];
      }
    }
  }
  out[idx] = fmaxf(acc, 0.f);
}

// ---------------------------------------------------------------- batchnorm
__global__ void bn_stats(const float* __restrict__ x, float* __restrict__ mean,
                         float* __restrict__ invstd, int HW, int CHW, int nPerC) {
  int c = blockIdx.x;
  int tid = threadIdx.x;
  float s = 0.f, sq = 0.f;
  for (int e = tid; e < nPerC; e += 256) {
    int b = e / HW;
    int i = e - b * HW;
    float v = x[(size_t)b * CHW + (size_t)c * HW + i];
    s += v; sq += v * v;
  }
  __shared__ float ls[256], lq[256];
  ls[tid] = s; lq[tid] = sq;
  __syncthreads();
  for (int st = 128; st > 0; st >>= 1) {
    if (tid < st) { ls[tid] += ls[tid + st]; lq[tid] += lq[tid + st]; }
    __syncthreads();
  }
  if (tid == 0) {
    float n = (float)nPerC;
    float m = ls[0] / n;
    float var = lq[0] / n - m * m;
    mean[c] = m;
    invstd[c] = rsqrtf(var + 1e-5f);
  }
}

__global__ void bn_norm(float* __restrict__ x, const float* __restrict__ mean,
                        const float* __restrict__ invstd, const float* __restrict__ g,
                        const float* __restrict__ beta, int C, int HW, int total) {
  int idx = blockIdx.x * blockDim.x + threadIdx.x;
  if (idx >= total) return;
  int c = (idx / HW) % C;
  x[idx] = (x[idx] - mean[c]) * invstd[c] * g[c] + beta[c];
}

// ---------------------------------------------------------------- feature / rel build
__global__ void build_obj(const float* __restrict__ x4, float* __restrict__ obj) {
  // x4 [128][256][25] -> obj [128][25][258]
  int idx = blockIdx.x * blockDim.x + threadIdx.x;
  int total = BATCH * 25 * 258;
  if (idx >= total) return;
  int d = idx % 258; int t = idx / 258;
  int i = t % 25; int b = t / 25;
  float v;
  if (d < 256)       v = x4[((size_t)b * 256 + d) * 25 + i];
  else if (d == 256) v = (float)(i / 5) * 0.5f - 1.f;
  else               v = (float)(i % 5) * 0.5f - 1.f;
  obj[idx] = v;
}

__global__ void build_rel_chunk(const float* __restrict__ obj, const float* __restrict__ q,
                                f16* __restrict__ rel, int rowStart, int nRows) {
  // rel [nRows][544]; global row = rowStart + local = b*625 + i*25 + j
  long idx = (long)blockIdx.x * blockDim.x + threadIdx.x;
  long total = (long)nRows * 544;
  if (idx >= total) return;
  int k = (int)(idx % 544);
  long t = idx / 544;
  long grow = rowStart + t;
  int pair = (int)(grow % 625);
  int b = (int)(grow / 625);
  int i = pair / 25, j = pair % 25;
  float v = 0.f;
  if (k < 258)       v = obj[((size_t)b * 25 + j) * 258 + k];
  else if (k < 516)  v = obj[((size_t)b * 25 + i) * 258 + (k - 258)];
  else if (k < 527)  v = q[b * 11 + (k - 516)];
  rel[idx] = (f16)v;
}

// ---------------------------------------------------------------- weight conversion (fp32 -> padded fp16)
__global__ void pad_w_f16(const float* __restrict__ w, f16* __restrict__ o,
                          int N, int K, int Kp, long total) {
  long idx = (long)blockIdx.x * blockDim.x + threadIdx.x;
  if (idx >= total) return;
  int k = (int)(idx % Kp);
  int n = (int)(idx / Kp);
  float v = (n < N && k < K) ? w[(size_t)n * K + k] : 0.f;
  o[idx] = (f16)v;
}

__global__ void pad_bias(const float* __restrict__ b, float* __restrict__ o, int N, int Np) {
  int i = blockIdx.x * blockDim.x + threadIdx.x;
  if (i < Np) o[i] = (i < N) ? b[i] : 0.f;
}

// ---------------------------------------------------------------- fp16 MFMA GEMM (m97 structure)
// C[m][n] = relu(sum_k A[m][k] * W[n][k] + bias[n]), output fp16.
// A [M][K], W [N][K] fp16 row-major. M%128==0, N%128==0, K%32==0.
__device__ __forceinline__ void load_lds16(const void* g, void* l) {
  __builtin_amdgcn_global_load_lds((const __attribute__((address_space(1))) unsigned int*)g,
                                   (__attribute__((address_space(3))) unsigned int*)l,
                                   16, 0, 0);
}

__global__ __launch_bounds__(256) void gemm_f16(const f16* __restrict__ A,
                                                const f16* __restrict__ Bw,
                                                const float* __restrict__ bias,
                                                f16* __restrict__ C,
                                                int M, int N, int K) {
  __shared__ __align__(16) f16 As[128 * 32];
  __shared__ __align__(16) f16 Bs[128 * 32];
  int tid = threadIdx.x;
  int wv = tid >> 6, l = tid & 63;
  int bm = blockIdx.x, bn = blockIdx.y;
  int wm = wv >> 1, wn = wv & 1;
  int lr = l & 15, lk = l >> 4;

  // staging: 16B-chunk index e = (wv*2+q)*64 + l ; row = e>>2 (4 chunks per 32-elem row), ch = e&3
  int e0 = (wv * 2) * 64 + l;
  int e1 = e0 + 64;
  int r0 = e0 >> 2, ch0 = e0 & 3;
  int r1 = e1 >> 2, ch1 = e1 & 3;
  const f16* ga0 = A + (size_t)(bm * 128 + r0) * K + ch0 * 8;
  const f16* ga1 = A + (size_t)(bm * 128 + r1) * K + ch1 * 8;
  const f16* gb0 = Bw + (size_t)(bn * 128 + r0) * K + ch0 * 8;
  const f16* gb1 = Bw + (size_t)(bn * 128 + r1) * K + ch1 * 8;
  f16* la0 = As + (wv * 2 + 0) * 512;
  f16* la1 = As + (wv * 2 + 1) * 512;
  f16* lb0 = Bs + (wv * 2 + 0) * 512;
  f16* lb1 = Bs + (wv * 2 + 1) * 512;

  f32x4 zero = {0.f, 0.f, 0.f, 0.f};
  f32x4 acc[4][4];
  #pragma unroll
  for (int i = 0; i < 4; ++i)
    #pragma unroll
    for (int j = 0; j < 4; ++j) acc[i][j] = zero;

  int nk = K >> 5;
  for (int kt = 0; kt < nk; ++kt) {
    __syncthreads();
    load_lds16(ga0, la0);
    load_lds16(ga1, la1);
    load_lds16(gb0, lb0);
    load_lds16(gb1, lb1);
    ga0 += 32; ga1 += 32; gb0 += 32; gb1 += 32;
    __syncthreads();
    f16x8 af[4], bf[4];
    #pragma unroll
    for (int i = 0; i < 4; ++i)
      af[i] = *(const f16x8*)&As[(wm * 64 + i * 16 + lr) * 32 + lk * 8];
    #pragma unroll
    for (int j = 0; j < 4; ++j)
      bf[j] = *(const f16x8*)&Bs[(wn * 64 + j * 16 + lr) * 32 + lk * 8];
    #pragma unroll
    for (int i = 0; i < 4; ++i)
      #pragma unroll
      for (int j = 0; j < 4; ++j)
        acc[i][j] = __builtin_amdgcn_mfma_f32_16x16x32_f16(af[i], bf[j], acc[i][j], 0, 0, 0);
  }

  int crow = bm * 128 + wm * 64;
  int ccol = bn * 128 + wn * 64;
  #pragma unroll
  for (int j = 0; j < 4; ++j) {
    int col = ccol + j * 16 + lr;
    float bj = bias[col];
    #pragma unroll
    for (int i = 0; i < 4; ++i) {
      int rowb = crow + i * 16 + lk * 4;
      #pragma unroll
      for (int r = 0; r < 4; ++r) {
        float v = acc[i][j][r] + bj;
        v = fmaxf(v, 0.f);
        C[(size_t)(rowb + r) * N + col] = (f16)v;
      }
    }
  }
}

// ---------------------------------------------------------------- pair sum (over 625 rows per batch)
__global__ void pair_sum(const f16* __restrict__ h4, float* __restrict__ hsumT,
                         int rowStart, int nRows, int gb0) {
  int b = gb0 + blockIdx.x;                      // global batch index
  int col = blockIdx.y * 256 + threadIdx.x;      // 0..2047
  int r0 = b * 625 - rowStart;    if (r0 < 0) r0 = 0;
  int r1 = (b + 1) * 625 - rowStart; if (r1 > nRows) r1 = nRows;
  if (r0 >= r1 || b >= BATCH) return;
  float acc = 0.f;
  for (int r = r0; r < r1; ++r) acc += (float)h4[(size_t)r * 2048 + col];
  hsumT[(size_t)col * BATCH + b] += acc;
}

// ---------------------------------------------------------------- fp32 FC on transposed activations
// inT [K][128], w [N][K], outT [N][128]; out = relu(in @ w.T + b)
__global__ void fc_t(const float* __restrict__ inT, const float* __restrict__ w,
                     const float* __restrict__ bias, float* __restrict__ outT,
                     int K, int N) {
  int n = blockIdx.x;
  int m = threadIdx.x;   // 128 threads
  const float* wr = w + (size_t)n * K;
  float acc = bias[n];
  int k = 0;
  for (; k + 4 <= K; k += 4) {
    acc += inT[(size_t)(k + 0) * BATCH + m] * wr[k + 0]
         + inT[(size_t)(k + 1) * BATCH + m] * wr[k + 1]
         + inT[(size_t)(k + 2) * BATCH + m] * wr[k + 2]
         + inT[(size_t)(k + 3) * BATCH + m] * wr[k + 3];
  }
  for (; k < K; ++k) acc += inT[(size_t)k * BATCH + m] * wr[k];
  outT[(size_t)n * BATCH + m] = fmaxf(acc, 0.f);
}

// ---------------------------------------------------------------- final linear + relu + log_softmax
__global__ void out_lsm(const float* __restrict__ f4T, const float* __restrict__ ow,
                        const float* __restrict__ ob, float* __restrict__ out) {
  int m = threadIdx.x;  // 128 threads, one sample each
  float z[10];
  #pragma unroll
  for (int c = 0; c < 10; ++c) {
    float acc = ob[c];
    for (int k = 0; k < 100; ++k) acc += f4T[(size_t)k * BATCH + m] * ow[c * 100 + k];
    z[c] = fmaxf(acc, 0.f);
  }
  float mx = z[0];
  #pragma unroll
  for (int c = 1; c < 10; ++c) mx = fmaxf(mx, z[c]);
  float s = 0.f;
  #pragma unroll
  for (int c = 0; c < 10; ++c) s += expf(z[c] - mx);
  float lse = mx + logf(s);
  #pragma unroll
  for (int c = 0; c < 10; ++c) out[m * 10 + c] = z[c] - lse;
}

// ---------------------------------------------------------------- host
extern "C" void kernel_launch(void* const* d_in, const int* in_sizes, int n_in,
                              void* d_out, int out_size, void* d_ws, size_t ws_size,
                              hipStream_t stream) {
  const float* image = (const float*)d_in[0];
  const float* questions = (const float*)d_in[1];
  const float* c1w = (const float*)d_in[2];  const float* c1b = (const float*)d_in[3];
  const float* bn1g = (const float*)d_in[4]; const float* bn1b = (const float*)d_in[5];
  const float* c2w = (const float*)d_in[6];  const float* c2b = (const float*)d_in[7];
  const float* bn2g = (const float*)d_in[8]; const float* bn2b = (const float*)d_in[9];
  const float* c3w = (const float*)d_in[10]; const float* c3b = (const float*)d_in[11];
  const float* bn3g = (const float*)d_in[12];const float* bn3b = (const float*)d_in[13];
  const float* c4w = (const float*)d_in[14]; const float* c4b = (const float*)d_in[15];
  const float* bn4g = (const float*)d_in[16];const float* bn4b = (const float*)d_in[17];
  const float* g1w = (const float*)d_in[18]; const float* g1b = (const float*)d_in[19];
  const float* g2w = (const float*)d_in[20]; const float* g2b = (const float*)d_in[21];
  const float* g3w = (const float*)d_in[22]; const float* g3b = (const float*)d_in[23];
  const float* g4w = (const float*)d_in[24]; const float* g4b = (const float*)d_in[25];
  const float* f1w = (const float*)d_in[26]; const float* f1b = (const float*)d_in[27];
  const float* f2w = (const float*)d_in[28]; const float* f2b = (const float*)d_in[29];
  const float* f3w = (const float*)d_in[30]; const float* f3b = (const float*)d_in[31];
  const float* f4w = (const float*)d_in[32]; const float* f4b = (const float*)d_in[33];
  const float* ow  = (const float*)d_in[34]; const float* ob  = (const float*)d_in[35];
  float* out = (float*)d_out;
  (void)in_sizes; (void)n_in; (void)out_size;

  // ---------------- workspace layout (adaptive chunk size, aliased regions) ----
  const size_t SZ_X1 = (size_t)BATCH * 32 * 40 * 40 * 4;   // 26.2 MB
  const size_t SZ_X2 = (size_t)BATCH * 64 * 20 * 20 * 4;   // 13.1 MB
  const size_t PERSIST =
      2048ull * 544 * 2 +            // wg1
      3ull * 2048 * 2048 * 2 +       // wg2..4
      4ull * 2048 * 4 +              // bgp
      2ull * 1024 * 4 +              // bn mean/invstd
      (size_t)BATCH * 25 * 258 * 4 + // obj
      2048ull * BATCH * 4 +          // hsumT
      (2000ull + 1000 + 500 + 100) * BATCH * 4 +  // f1T..f4T
      64ull * 256;                   // alignment slack

  auto need = [&](int CH) -> size_t {
    size_t sgemm = (size_t)CH * 2048 * 2;
    size_t SA = sgemm > SZ_X1 ? sgemm : SZ_X1;
    size_t SB = sgemm > SZ_X2 ? sgemm : SZ_X2;
    size_t SC = (size_t)CH * 544 * 2;
    return PERSIST + SA + SB + SC;
  };
  int CH = 1024;
  const int cands[4] = {16000, 8192, 4096, 2048};
  for (int ci = 0; ci < 4; ++ci) {
    if (need(cands[ci]) <= ws_size) { CH = cands[ci]; break; }
  }

  char* ws = (char*)d_ws;
  size_t off = 0;
  auto alloc = [&](size_t bytes) -> void* {
    void* p = ws + off;
    off += (bytes + 255) & ~(size_t)255;
    return p;
  };
  // persistent
  f16* wg1 = (f16*)alloc(2048ull * 544 * 2);
  f16* wg2 = (f16*)alloc(2048ull * 2048 * 2);
  f16* wg3 = (f16*)alloc(2048ull * 2048 * 2);
  f16* wg4 = (f16*)alloc(2048ull * 2048 * 2);
  float* bgp = (float*)alloc(4 * 2048 * 4);
  float* bnm = (float*)alloc(1024 * 4);
  float* bns = (float*)alloc(1024 * 4);
  float* obj = (float*)alloc((size_t)BATCH * 25 * 258 * 4);
  float* hsumT = (float*)alloc(2048ull * BATCH * 4);
  float* f1T = (float*)alloc(2000ull * BATCH * 4);
  float* f2T = (float*)alloc(1000ull * BATCH * 4);
  float* f3T = (float*)alloc(500ull * BATCH * 4);
  float* f4T = (float*)alloc(100ull * BATCH * 4);
  // big aliased regions
  size_t sgemm = (size_t)CH * 2048 * 2;
  size_t SA = sgemm > SZ_X1 ? sgemm : SZ_X1;
  size_t SB = sgemm > SZ_X2 ? sgemm : SZ_X2;
  char* regA = (char*)alloc(SA);
  char* regB = (char*)alloc(SB);
  f16* relc = (f16*)alloc((size_t)CH * 544 * 2);

  float* x1 = (float*)regA;   // conv phase
  float* x3 = (float*)regA;
  f16*   hA = (f16*)regA;     // gemm phase
  float* x2 = (float*)regB;
  float* x4 = (float*)regB;
  f16*   hB = (f16*)regB;

  // ---- weight conversion ----
  {
    long t1 = 2048L * 544;
    pad_w_f16<<<(int)((t1 + 255) / 256), 256, 0, stream>>>(g1w, wg1, 2000, 527, 544, t1);
    long t2 = 2048L * 2048;
    pad_w_f16<<<(int)((t2 + 255) / 256), 256, 0, stream>>>(g2w, wg2, 2000, 2000, 2048, t2);
    pad_w_f16<<<(int)((t2 + 255) / 256), 256, 0, stream>>>(g3w, wg3, 2000, 2000, 2048, t2);
    pad_w_f16<<<(int)((t2 + 255) / 256), 256, 0, stream>>>(g4w, wg4, 2000, 2000, 2048, t2);
    pad_bias<<<8, 256, 0, stream>>>(g1b, bgp + 0 * 2048, 2000, 2048);
    pad_bias<<<8, 256, 0, stream>>>(g2b, bgp + 1 * 2048, 2000, 2048);
    pad_bias<<<8, 256, 0, stream>>>(g3b, bgp + 2 * 2048, 2000, 2048);
    pad_bias<<<8, 256, 0, stream>>>(g4b, bgp + 3 * 2048, 2000, 2048);
  }

  // ---- conv stack ----
  {
    int t = BATCH * 32 * 40 * 40;
    conv3x3s2_relu<3><<<(t + 255) / 256, 256, 0, stream>>>(image, c1w, c1b, x1, 32, 80, 80);
    bn_stats<<<32, 256, 0, stream>>>(x1, bnm + 0, bns + 0, 1600, 32 * 1600, BATCH * 1600);
    bn_norm<<<(t + 255) / 256, 256, 0, stream>>>(x1, bnm + 0, bns + 0, bn1g, bn1b, 32, 1600, t);

    t = BATCH * 64 * 20 * 20;
    conv3x3s2_relu<32><<<(t + 255) / 256, 256, 0, stream>>>(x1, c2w, c2b, x2, 64, 40, 40);
    bn_stats<<<64, 256, 0, stream>>>(x2, bnm + 64, bns + 64, 400, 64 * 400, BATCH * 400);
    bn_norm<<<(t + 255) / 256, 256, 0, stream>>>(x2, bnm + 64, bns + 64, bn2g, bn2b, 64, 400, t);

    t = BATCH * 128 * 10 * 10;
    conv3x3s2_relu<64><<<(t + 255) / 256, 256, 0, stream>>>(x2, c3w, c3b, x3, 128, 20, 20);
    bn_stats<<<128, 256, 0, stream>>>(x3, bnm + 128, bns + 128, 100, 128 * 100, BATCH * 100);
    bn_norm<<<(t + 255) / 256, 256, 0, stream>>>(x3, bnm + 128, bns + 128, bn3g, bn3b, 128, 100, t);

    t = BATCH * 256 * 5 * 5;
    conv3x3s2_relu<128><<<(t + 255) / 256, 256, 0, stream>>>(x3, c4w, c4b, x4, 256, 10, 10);
    bn_stats<<<256, 256, 0, stream>>>(x4, bnm + 512, bns + 512, 25, 256 * 25, BATCH * 25);
    bn_norm<<<(t + 255) / 256, 256, 0, stream>>>(x4, bnm + 512, bns + 512, bn4g, bn4b, 256, 25, t);
  }

  // ---- feature build ----
  {
    int t = BATCH * 25 * 258;
    build_obj<<<(t + 255) / 256, 256, 0, stream>>>(x4, obj);
  }

  // ---- g-MLP (chunked) + pair sum ----
  hipMemsetAsync(hsumT, 0, 2048ull * BATCH * 4, stream);
  for (int start = 0; start < 80000; start += CH) {
    int M = 80000 - start;
    if (M > CH) M = CH;
    long tr = (long)M * 544;
    build_rel_chunk<<<(int)((tr + 255) / 256), 256, 0, stream>>>(obj, questions, relc, start, M);
    dim3 gg(M / 128, 16);
    gemm_f16<<<gg, 256, 0, stream>>>(relc, wg1, bgp + 0 * 2048, hA, M, 2048, 544);
    gemm_f16<<<gg, 256, 0, stream>>>(hA, wg2, bgp + 1 * 2048, hB, M, 2048, 2048);
    gemm_f16<<<gg, 256, 0, stream>>>(hB, wg3, bgp + 2 * 2048, hA, M, 2048, 2048);
    gemm_f16<<<gg, 256, 0, stream>>>(hA, wg4, bgp + 3 * 2048, hB, M, 2048, 2048);
    int gb0 = start / 625;
    int gb1 = (start + M - 1) / 625;
    dim3 sg(gb1 - gb0 + 1, 8);
    pair_sum<<<sg, 256, 0, stream>>>(hB, hsumT, start, M, gb0);
  }

  // ---- f-MLP (fp32, transposed) ----
  fc_t<<<2000, 128, 0, stream>>>(hsumT, f1w, f1b, f1T, 2000, 2000);
  fc_t<<<1000, 128, 0, stream>>>(f1T, f2w, f2b, f2T, 2000, 1000);
  fc_t<<<500, 128, 0, stream>>>(f2T, f3w, f3b, f3T, 1000, 500);
  fc_t<<<100, 128, 0, stream>>>(f3T, f4w, f4b, f4T, 500, 100);
  out_lsm<<<1, 128, 0, stream>>>(f4T, ow, ob, out);
}

// Round 4
// 5183.634 us; speedup vs baseline: 1.5436x; 1.5436x over previous
//
#include <hip/hip_runtime.h>
#include <hip/hip_fp16.h>
#include <cstdint>

typedef _Float16 f16;
typedef _Float16 f16x8 __attribute__((ext_vector_type(8)));
typedef float f32x4 __attribute__((ext_vector_type(4)));

#define BATCH 128

// ---------------------------------------------------------------- weight prep
__global__ void pad_w_f16(const float* __restrict__ w, f16* __restrict__ o,
                          int N, int K, int Kp, long total) {
  long idx = (long)blockIdx.x * blockDim.x + threadIdx.x;
  if (idx >= total) return;
  int k = (int)(idx % Kp);
  int n = (int)(idx / Kp);
  float v = (n < N && k < K) ? w[(size_t)n * K + k] : 0.f;
  o[idx] = (f16)v;
}

__global__ void pad_bias(const float* __restrict__ b, float* __restrict__ o, int N, int Np) {
  int i = blockIdx.x * blockDim.x + threadIdx.x;
  if (i < Np) o[i] = (i < N) ? b[i] : 0.f;
}

// conv weight [CO][CI][3][3] -> wp [COp][Kp], k = tap*CI + ci  (tap = ky*3+kx)
__global__ void prep_convw(const float* __restrict__ w, f16* __restrict__ o,
                           int CO, int CI, int COp, int Kp) {
  int idx = blockIdx.x * blockDim.x + threadIdx.x;
  int total = COp * Kp;
  if (idx >= total) return;
  int k = idx % Kp;
  int co = idx / Kp;
  float v = 0.f;
  if (co < CO && k < 9 * CI) {
    int tap = k / CI, ci = k % CI;
    v = w[((size_t)co * CI + ci) * 9 + tap];
  }
  o[idx] = (f16)v;
}

// ---------------------------------------------------------------- im2col
// conv1: image fp32 NCHW [128][3][80][80] -> A1 [204800][32] f16 (k = tap*3+ci)
__global__ void im2col1(const float* __restrict__ img, f16* __restrict__ A) {
  int idx = blockIdx.x * blockDim.x + threadIdx.x;
  const int total = 204800 * 32;
  if (idx >= total) return;
  int k = idx & 31;
  int m = idx >> 5;
  int ox = m % 40; int t = m / 40;
  int oy = t % 40; int b = t / 40;
  float v = 0.f;
  if (k < 27) {
    int tap = k / 3, ci = k % 3;
    int iy = oy * 2 - 1 + tap / 3;
    int ix = ox * 2 - 1 + tap % 3;
    if ((unsigned)iy < 80u && (unsigned)ix < 80u)
      v = img[(((size_t)b * 3 + ci) * 80 + iy) * 80 + ix];
  }
  A[idx] = (f16)v;
}

// NHWC f16 [B][H][W][Cs] -> A [M][Kp], k = tap*Cv + ci, Cv channels valid
__global__ void im2col_nhwc(const f16* __restrict__ y, f16* __restrict__ A,
                            int H, int W, int OH, int OW, int Cs, int Cv, int Kp,
                            long total) {
  long idx = (long)blockIdx.x * blockDim.x + threadIdx.x;
  if (idx >= total) return;
  int G = Cv >> 3;
  int cg = (int)(idx % G);
  long t = idx / G;
  int tap = (int)(t % 9);
  int m = (int)(t / 9);
  int ox = m % OW; int t2 = m / OW;
  int oy = t2 % OH; int b = t2 / OH;
  int iy = oy * 2 - 1 + tap / 3;
  int ix = ox * 2 - 1 + tap % 3;
  f16x8 v = {};
  if ((unsigned)iy < (unsigned)H && (unsigned)ix < (unsigned)W)
    v = *(const f16x8*)&y[(((size_t)b * H + iy) * W + ix) * Cs + cg * 8];
  *(f16x8*)&A[(size_t)m * Kp + tap * Cv + cg * 8] = v;
}

// ---------------------------------------------------------------- batchnorm (NHWC, two-stage)
// stage 1: per-1024-row-block partial sums per channel
__global__ void bn_part(const f16* __restrict__ y, float* __restrict__ psum,
                        float* __restrict__ psq, int M, int Cs, int RPB) {
  int G = Cs >> 3;          // channel groups of 8
  int R = 256 / G;          // row lanes
  int tid = threadIdx.x;
  int g = tid % G, r = tid / G;
  int row0 = blockIdx.x * RPB;
  int rowEnd = row0 + RPB; if (rowEnd > M) rowEnd = M;
  float s[8], q[8];
  #pragma unroll
  for (int e = 0; e < 8; ++e) { s[e] = 0.f; q[e] = 0.f; }
  for (int row = row0 + r; row < rowEnd; row += R) {
    f16x8 v = *(const f16x8*)&y[(size_t)row * Cs + g * 8];
    #pragma unroll
    for (int e = 0; e < 8; ++e) { float f = (float)v[e]; s[e] += f; q[e] += f * f; }
  }
  __shared__ float ls[256 * 8];
  __shared__ float lq[256 * 8];
  #pragma unroll
  for (int e = 0; e < 8; ++e) { ls[tid * 8 + e] = s[e]; lq[tid * 8 + e] = q[e]; }
  __syncthreads();
  for (int st = R / 2; st > 0; st >>= 1) {
    if (r < st) {
      int o = tid * 8, p = (tid + st * G) * 8;
      #pragma unroll
      for (int e = 0; e < 8; ++e) { ls[o + e] += ls[p + e]; lq[o + e] += lq[p + e]; }
    }
    __syncthreads();
  }
  if (r == 0) {
    #pragma unroll
    for (int e = 0; e < 8; ++e) {
      psum[(size_t)blockIdx.x * Cs + g * 8 + e] = ls[tid * 8 + e];
      psq [(size_t)blockIdx.x * Cs + g * 8 + e] = lq[tid * 8 + e];
    }
  }
}

// stage 2: finalize scale/shift  (scale=g*invstd, shift=beta-mean*scale; 0 for pad chans)
__global__ void bn_final(const float* __restrict__ psum, const float* __restrict__ psq,
                         const float* __restrict__ g, const float* __restrict__ beta,
                         float* __restrict__ scale, float* __restrict__ shift,
                         int nblk, int Cs, int Cv, int M) {
  int c = threadIdx.x;
  if (c >= Cs) return;
  float s = 0.f, q = 0.f;
  for (int b = 0; b < nblk; ++b) { s += psum[(size_t)b * Cs + c]; q += psq[(size_t)b * Cs + c]; }
  float inv = 1.f / (float)M;
  float m = s * inv;
  float var = q * inv - m * m;
  if (c < Cv) {
    float sc = g[c] * rsqrtf(var + 1e-5f);
    scale[c] = sc;
    shift[c] = beta[c] - m * sc;
  } else {
    scale[c] = 0.f;
    shift[c] = 0.f;
  }
}

// stage 3: apply in place
__global__ void bn_apply(f16* __restrict__ y, const float* __restrict__ scale,
                         const float* __restrict__ shift, long totalGroups, int Cs) {
  long idx = (long)blockIdx.x * blockDim.x + threadIdx.x;
  if (idx >= totalGroups) return;
  int G = Cs >> 3;
  int cg = (int)(idx % G);
  long m = idx / G;
  f16x8 v = *(const f16x8*)&y[m * Cs + cg * 8];
  #pragma unroll
  for (int e = 0; e < 8; ++e)
    v[e] = (f16)((float)v[e] * scale[cg * 8 + e] + shift[cg * 8 + e]);
  *(f16x8*)&y[m * Cs + cg * 8] = v;
}

// ---------------------------------------------------------------- rel build (reads y4 NHWC f16)
__global__ void build_rel_chunk(const f16* __restrict__ y4, const float* __restrict__ q,
                                f16* __restrict__ rel, int rowStart, int nRows) {
  long idx = (long)blockIdx.x * blockDim.x + threadIdx.x;
  long total = (long)nRows * 544;
  if (idx >= total) return;
  int k = (int)(idx % 544);
  long t = idx / 544;
  long grow = rowStart + t;
  int pair = (int)(grow % 625);
  int b = (int)(grow / 625);
  int i = pair / 25, j = pair % 25;
  f16 v = (f16)0.f;
  if (k < 256)       v = y4[((size_t)b * 25 + j) * 256 + k];
  else if (k == 256) v = (f16)((float)(j / 5) * 0.5f - 1.f);
  else if (k == 257) v = (f16)((float)(j % 5) * 0.5f - 1.f);
  else if (k < 514)  v = y4[((size_t)b * 25 + i) * 256 + (k - 258)];
  else if (k == 514) v = (f16)((float)(i / 5) * 0.5f - 1.f);
  else if (k == 515) v = (f16)((float)(i % 5) * 0.5f - 1.f);
  else if (k < 527)  v = (f16)q[b * 11 + (k - 516)];
  rel[idx] = v;
}

// ---------------------------------------------------------------- fp16 MFMA GEMM (m97 structure)
// C[m][n] = relu(sum_k A[m][k]*W[n][k] + bias[n]) -> f16. M%128==0, N%128==0, K%32==0.
__device__ __forceinline__ void load_lds16(const void* g, void* l) {
  __builtin_amdgcn_global_load_lds((const __attribute__((address_space(1))) unsigned int*)g,
                                   (__attribute__((address_space(3))) unsigned int*)l,
                                   16, 0, 0);
}

__global__ __launch_bounds__(256) void gemm_f16(const f16* __restrict__ A,
                                                const f16* __restrict__ Bw,
                                                const float* __restrict__ bias,
                                                f16* __restrict__ C,
                                                int M, int N, int K) {
  __shared__ __align__(16) f16 As[128 * 32];
  __shared__ __align__(16) f16 Bs[128 * 32];
  int tid = threadIdx.x;
  int wv = tid >> 6, l = tid & 63;
  int bm = blockIdx.x, bn = blockIdx.y;
  int wm = wv >> 1, wn = wv & 1;
  int lr = l & 15, lk = l >> 4;

  int e0 = (wv * 2) * 64 + l;
  int e1 = e0 + 64;
  int r0 = e0 >> 2, ch0 = e0 & 3;
  int r1 = e1 >> 2, ch1 = e1 & 3;
  const f16* ga0 = A + (size_t)(bm * 128 + r0) * K + ch0 * 8;
  const f16* ga1 = A + (size_t)(bm * 128 + r1) * K + ch1 * 8;
  const f16* gb0 = Bw + (size_t)(bn * 128 + r0) * K + ch0 * 8;
  const f16* gb1 = Bw + (size_t)(bn * 128 + r1) * K + ch1 * 8;
  f16* la0 = As + (wv * 2 + 0) * 512;
  f16* la1 = As + (wv * 2 + 1) * 512;
  f16* lb0 = Bs + (wv * 2 + 0) * 512;
  f16* lb1 = Bs + (wv * 2 + 1) * 512;

  f32x4 zero = {0.f, 0.f, 0.f, 0.f};
  f32x4 acc[4][4];
  #pragma unroll
  for (int i = 0; i < 4; ++i)
    #pragma unroll
    for (int j = 0; j < 4; ++j) acc[i][j] = zero;

  int nk = K >> 5;
  for (int kt = 0; kt < nk; ++kt) {
    __syncthreads();
    load_lds16(ga0, la0);
    load_lds16(ga1, la1);
    load_lds16(gb0, lb0);
    load_lds16(gb1, lb1);
    ga0 += 32; ga1 += 32; gb0 += 32; gb1 += 32;
    __syncthreads();
    f16x8 af[4], bf[4];
    #pragma unroll
    for (int i = 0; i < 4; ++i)
      af[i] = *(const f16x8*)&As[(wm * 64 + i * 16 + lr) * 32 + lk * 8];
    #pragma unroll
    for (int j = 0; j < 4; ++j)
      bf[j] = *(const f16x8*)&Bs[(wn * 64 + j * 16 + lr) * 32 + lk * 8];
    #pragma unroll
    for (int i = 0; i < 4; ++i)
      #pragma unroll
      for (int j = 0; j < 4; ++j)
        acc[i][j] = __builtin_amdgcn_mfma_f32_16x16x32_f16(af[i], bf[j], acc[i][j], 0, 0, 0);
  }

  int crow = bm * 128 + wm * 64;
  int ccol = bn * 128 + wn * 64;
  #pragma unroll
  for (int j = 0; j < 4; ++j) {
    int col = ccol + j * 16 + lr;
    float bj = bias[col];
    #pragma unroll
    for (int i = 0; i < 4; ++i) {
      int rowb = crow + i * 16 + lk * 4;
      #pragma unroll
      for (int r = 0; r < 4; ++r) {
        float v = acc[i][j][r] + bj;
        v = fmaxf(v, 0.f);
        C[(size_t)(rowb + r) * N + col] = (f16)v;
      }
    }
  }
}

// ---------------------------------------------------------------- pair sum
__global__ void pair_sum(const f16* __restrict__ h4, float* __restrict__ hsumT,
                         int rowStart, int nRows, int gb0) {
  int b = gb0 + blockIdx.x;
  int col = blockIdx.y * 256 + threadIdx.x;
  int r0 = b * 625 - rowStart;    if (r0 < 0) r0 = 0;
  int r1 = (b + 1) * 625 - rowStart; if (r1 > nRows) r1 = nRows;
  if (r0 >= r1 || b >= BATCH) return;
  float acc = 0.f;
  for (int r = r0; r < r1; ++r) acc += (float)h4[(size_t)r * 2048 + col];
  hsumT[(size_t)col * BATCH + b] += acc;
}

// ---------------------------------------------------------------- fp32 FC (transposed act)
__global__ void fc_t(const float* __restrict__ inT, const float* __restrict__ w,
                     const float* __restrict__ bias, float* __restrict__ outT,
                     int K, int N) {
  int n = blockIdx.x;
  int m = threadIdx.x;
  const float* wr = w + (size_t)n * K;
  float acc = bias[n];
  int k = 0;
  for (; k + 4 <= K; k += 4) {
    acc += inT[(size_t)(k + 0) * BATCH + m] * wr[k + 0]
         + inT[(size_t)(k + 1) * BATCH + m] * wr[k + 1]
         + inT[(size_t)(k + 2) * BATCH + m] * wr[k + 2]
         + inT[(size_t)(k + 3) * BATCH + m] * wr[k + 3];
  }
  for (; k < K; ++k) acc += inT[(size_t)k * BATCH + m] * wr[k];
  outT[(size_t)n * BATCH + m] = fmaxf(acc, 0.f);
}

// ---------------------------------------------------------------- final linear + log_softmax
__global__ void out_lsm(const float* __restrict__ f4T, const float* __restrict__ ow,
                        const float* __restrict__ ob, float* __restrict__ out) {
  int m = threadIdx.x;
  float z[10];
  #pragma unroll
  for (int c = 0; c < 10; ++c) {
    float acc = ob[c];
    for (int k = 0; k < 100; ++k) acc += f4T[(size_t)k * BATCH + m] * ow[c * 100 + k];
    z[c] = fmaxf(acc, 0.f);
  }
  float mx = z[0];
  #pragma unroll
  for (int c = 1; c < 10; ++c) mx = fmaxf(mx, z[c]);
  float s = 0.f;
  #pragma unroll
  for (int c = 0; c < 10; ++c) s += expf(z[c] - mx);
  float lse = mx + logf(s);
  #pragma unroll
  for (int c = 0; c < 10; ++c) out[m * 10 + c] = z[c] - lse;
}

// ---------------------------------------------------------------- host
extern "C" void kernel_launch(void* const* d_in, const int* in_sizes, int n_in,
                              void* d_out, int out_size, void* d_ws, size_t ws_size,
                              hipStream_t stream) {
  const float* image = (const float*)d_in[0];
  const float* questions = (const float*)d_in[1];
  const float* c1w = (const float*)d_in[2];  const float* c1b = (const float*)d_in[3];
  const float* bn1g = (const float*)d_in[4]; const float* bn1b = (const float*)d_in[5];
  const float* c2w = (const float*)d_in[6];  const float* c2b = (const float*)d_in[7];
  const float* bn2g = (const float*)d_in[8]; const float* bn2b = (const float*)d_in[9];
  const float* c3w = (const float*)d_in[10]; const float* c3b = (const float*)d_in[11];
  const float* bn3g = (const float*)d_in[12];const float* bn3b = (const float*)d_in[13];
  const float* c4w = (const float*)d_in[14]; const float* c4b = (const float*)d_in[15];
  const float* bn4g = (const float*)d_in[16];const float* bn4b = (const float*)d_in[17];
  const float* g1w = (const float*)d_in[18]; const float* g1b = (const float*)d_in[19];
  const float* g2w = (const float*)d_in[20]; const float* g2b = (const float*)d_in[21];
  const float* g3w = (const float*)d_in[22]; const float* g3b = (const float*)d_in[23];
  const float* g4w = (const float*)d_in[24]; const float* g4b = (const float*)d_in[25];
  const float* f1w = (const float*)d_in[26]; const float* f1b = (const float*)d_in[27];
  const float* f2w = (const float*)d_in[28]; const float* f2b = (const float*)d_in[29];
  const float* f3w = (const float*)d_in[30]; const float* f3b = (const float*)d_in[31];
  const float* f4w = (const float*)d_in[32]; const float* f4b = (const float*)d_in[33];
  const float* ow  = (const float*)d_in[34]; const float* ob  = (const float*)d_in[35];
  float* out = (float*)d_out;
  (void)in_sizes; (void)n_in; (void)out_size;

  // ---------------- workspace sizing ----
  const size_t MB = 1024ull * 1024;
  const size_t PERSIST =
      2048ull * 544 * 2 + 3ull * 2048 * 2048 * 2 +   // g-weights
      4ull * 2048 * 4 +                               // g-bias
      (128ull * 32 + 128 * 288 + 128 * 576 + 256 * 1152) * 2 +  // conv weights
      (128ull + 128 + 128 + 256) * 4 +                // conv biases
      2ull * 205 * 256 * 4 +                          // bn partials
      2ull * 256 * 4 +                                // scale/shift
      3200ull * 256 * 2 +                             // y4
      2048ull * BATCH * 4 +                           // hsumT
      (2000ull + 1000 + 500 + 100) * BATCH * 4 +      // f1T..f4T
      64ull * 256;                                    // slack

  auto need = [&](int CH) -> size_t {
    size_t sg = (size_t)CH * 4096;
    size_t SA = sg > 56 * MB ? sg : 56 * MB;
    size_t SB = sg > 30 * MB ? sg : 30 * MB;
    size_t sc = (size_t)CH * 1088;
    size_t SC = sc > 14 * MB ? sc : 14 * MB;
    return PERSIST + SA + SB + SC;
  };
  int CH = 1024;
  const int cands[4] = {16000, 8192, 4096, 2048};
  for (int ci = 0; ci < 4; ++ci)
    if (need(cands[ci]) <= ws_size) { CH = cands[ci]; break; }

  char* ws = (char*)d_ws;
  size_t off = 0;
  auto alloc = [&](size_t bytes) -> void* {
    void* p = ws + off;
    off += (bytes + 255) & ~(size_t)255;
    return p;
  };
  f16* wg1 = (f16*)alloc(2048ull * 544 * 2);
  f16* wg2 = (f16*)alloc(2048ull * 2048 * 2);
  f16* wg3 = (f16*)alloc(2048ull * 2048 * 2);
  f16* wg4 = (f16*)alloc(2048ull * 2048 * 2);
  float* bgp = (float*)alloc(4 * 2048 * 4);
  f16* wp1 = (f16*)alloc(128ull * 32 * 2);
  f16* wp2 = (f16*)alloc(128ull * 288 * 2);
  f16* wp3 = (f16*)alloc(128ull * 576 * 2);
  f16* wp4 = (f16*)alloc(256ull * 1152 * 2);
  float* bc1p = (float*)alloc(128 * 4);
  float* bc2p = (float*)alloc(128 * 4);
  float* bc3p = (float*)alloc(128 * 4);
  float* bc4p = (float*)alloc(256 * 4);
  float* psum = (float*)alloc(205ull * 256 * 4);
  float* psq  = (float*)alloc(205ull * 256 * 4);
  float* scl  = (float*)alloc(256 * 4);
  float* shf  = (float*)alloc(256 * 4);
  f16* y4 = (f16*)alloc(3200ull * 256 * 2);
  float* hsumT = (float*)alloc(2048ull * BATCH * 4);
  float* f1T = (float*)alloc(2000ull * BATCH * 4);
  float* f2T = (float*)alloc(1000ull * BATCH * 4);
  float* f3T = (float*)alloc(500ull * BATCH * 4);
  float* f4T = (float*)alloc(100ull * BATCH * 4);

  size_t sg = (size_t)CH * 4096;
  size_t SA = sg > 56 * MB ? sg : 56 * MB;
  size_t SB = sg > 30 * MB ? sg : 30 * MB;
  size_t sc = (size_t)CH * 1088;
  size_t SC = sc > 14 * MB ? sc : 14 * MB;
  char* regA = (char*)alloc(SA);
  char* regB = (char*)alloc(SB);
  char* regC = (char*)alloc(SC);

  // conv-phase aliases
  f16* y1 = (f16*)regA;                 // [204800][128]
  f16* A1 = (f16*)regB;                 // [204800][32]
  f16* A2 = (f16*)regB;                 // [51200][288]   (A1 dead)
  f16* y2 = (f16*)regC;                 // [51200][128]
  f16* A3 = (f16*)regA;                 // [12800][576]   (y1 dead)
  f16* y3 = (f16*)regB;                 // [12800][128]   (A2 dead)
  f16* A4 = (f16*)(regB + 4 * MB);      // [3200][1152]
  // gemm-phase aliases
  f16* hA = (f16*)regA;
  f16* hB = (f16*)regB;
  f16* relc = (f16*)regC;

  // ---- weight prep ----
  {
    long t1 = 2048L * 544;
    pad_w_f16<<<(int)((t1 + 255) / 256), 256, 0, stream>>>(g1w, wg1, 2000, 527, 544, t1);
    long t2 = 2048L * 2048;
    pad_w_f16<<<(int)((t2 + 255) / 256), 256, 0, stream>>>(g2w, wg2, 2000, 2000, 2048, t2);
    pad_w_f16<<<(int)((t2 + 255) / 256), 256, 0, stream>>>(g3w, wg3, 2000, 2000, 2048, t2);
    pad_w_f16<<<(int)((t2 + 255) / 256), 256, 0, stream>>>(g4w, wg4, 2000, 2000, 2048, t2);
    pad_bias<<<8, 256, 0, stream>>>(g1b, bgp + 0 * 2048, 2000, 2048);
    pad_bias<<<8, 256, 0, stream>>>(g2b, bgp + 1 * 2048, 2000, 2048);
    pad_bias<<<8, 256, 0, stream>>>(g3b, bgp + 2 * 2048, 2000, 2048);
    pad_bias<<<8, 256, 0, stream>>>(g4b, bgp + 3 * 2048, 2000, 2048);
    prep_convw<<<(128 * 32 + 255) / 256, 256, 0, stream>>>(c1w, wp1, 32, 3, 128, 32);
    prep_convw<<<(128 * 288 + 255) / 256, 256, 0, stream>>>(c2w, wp2, 64, 32, 128, 288);
    prep_convw<<<(128 * 576 + 255) / 256, 256, 0, stream>>>(c3w, wp3, 128, 64, 128, 576);
    prep_convw<<<(256 * 1152 + 255) / 256, 256, 0, stream>>>(c4w, wp4, 256, 128, 256, 1152);
    pad_bias<<<1, 256, 0, stream>>>(c1b, bc1p, 32, 128);
    pad_bias<<<1, 256, 0, stream>>>(c2b, bc2p, 64, 128);
    pad_bias<<<1, 256, 0, stream>>>(c3b, bc3p, 128, 128);
    pad_bias<<<1, 256, 0, stream>>>(c4b, bc4p, 256, 256);
  }

  // ---- conv stack: im2col + gemm + BN, NHWC f16 ----
  // L1: 80x80x3 -> 40x40x32 (stored [204800][128], 32 valid)
  im2col1<<<(204800 * 32 + 255) / 256, 256, 0, stream>>>(image, A1);
  { dim3 g(1600, 1); gemm_f16<<<g, 256, 0, stream>>>(A1, wp1, bc1p, y1, 204800, 128, 32); }
  bn_part<<<200, 256, 0, stream>>>(y1, psum, psq, 204800, 128, 1024);
  bn_final<<<1, 256, 0, stream>>>(psum, psq, bn1g, bn1b, scl, shf, 200, 128, 32, 204800);
  bn_apply<<<(int)((204800L * 16 + 255) / 256), 256, 0, stream>>>(y1, scl, shf, 204800L * 16, 128);
  // L2: 40x40x32 -> 20x20x64
  { long t = 51200L * 9 * 4;
    im2col_nhwc<<<(int)((t + 255) / 256), 256, 0, stream>>>(y1, A2, 40, 40, 20, 20, 128, 32, 288, t); }
  { dim3 g(400, 1); gemm_f16<<<g, 256, 0, stream>>>(A2, wp2, bc2p, y2, 51200, 128, 288); }
  bn_part<<<50, 256, 0, stream>>>(y2, psum, psq, 51200, 128, 1024);
  bn_final<<<1, 256, 0, stream>>>(psum, psq, bn2g, bn2b, scl, shf, 50, 128, 64, 51200);
  bn_apply<<<(int)((51200L * 16 + 255) / 256), 256, 0, stream>>>(y2, scl, shf, 51200L * 16, 128);
  // L3: 20x20x64 -> 10x10x128
  { long t = 12800L * 9 * 8;
    im2col_nhwc<<<(int)((t + 255) / 256), 256, 0, stream>>>(y2, A3, 20, 20, 10, 10, 128, 64, 576, t); }
  { dim3 g(100, 1); gemm_f16<<<g, 256, 0, stream>>>(A3, wp3, bc3p, y3, 12800, 128, 576); }
  bn_part<<<13, 256, 0, stream>>>(y3, psum, psq, 12800, 128, 1024);
  bn_final<<<1, 256, 0, stream>>>(psum, psq, bn3g, bn3b, scl, shf, 13, 128, 128, 12800);
  bn_apply<<<(int)((12800L * 16 + 255) / 256), 256, 0, stream>>>(y3, scl, shf, 12800L * 16, 128);
  // L4: 10x10x128 -> 5x5x256
  { long t = 3200L * 9 * 16;
    im2col_nhwc<<<(int)((t + 255) / 256), 256, 0, stream>>>(y3, A4, 10, 10, 5, 5, 128, 128, 1152, t); }
  { dim3 g(25, 2); gemm_f16<<<g, 256, 0, stream>>>(A4, wp4, bc4p, y4, 3200, 256, 1152); }
  bn_part<<<4, 256, 0, stream>>>(y4, psum, psq, 3200, 256, 1024);
  bn_final<<<1, 256, 0, stream>>>(psum, psq, bn4g, bn4b, scl, shf, 4, 256, 256, 3200);
  bn_apply<<<(int)((3200L * 32 + 255) / 256), 256, 0, stream>>>(y4, scl, shf, 3200L * 32, 256);

  // ---- g-MLP (chunked) + pair sum ----
  hipMemsetAsync(hsumT, 0, 2048ull * BATCH * 4, stream);
  for (int start = 0; start < 80000; start += CH) {
    int M = 80000 - start;
    if (M > CH) M = CH;
    long tr = (long)M * 544;
    build_rel_chunk<<<(int)((tr + 255) / 256), 256, 0, stream>>>(y4, questions, relc, start, M);
    dim3 gg(M / 128, 16);
    gemm_f16<<<gg, 256, 0, stream>>>(relc, wg1, bgp + 0 * 2048, hA, M, 2048, 544);
    gemm_f16<<<gg, 256, 0, stream>>>(hA, wg2, bgp + 1 * 2048, hB, M, 2048, 2048);
    gemm_f16<<<gg, 256, 0, stream>>>(hB, wg3, bgp + 2 * 2048, hA, M, 2048, 2048);
    gemm_f16<<<gg, 256, 0, stream>>>(hA, wg4, bgp + 3 * 2048, hB, M, 2048, 2048);
    int gb0 = start / 625;
    int gb1 = (start + M - 1) / 625;
    dim3 sgr(gb1 - gb0 + 1, 8);
    pair_sum<<<sgr, 256, 0, stream>>>(hB, hsumT, start, M, gb0);
  }

  // ---- f-MLP ----
  fc_t<<<2000, 128, 0, stream>>>(hsumT, f1w, f1b, f1T, 2000, 2000);
  fc_t<<<1000, 128, 0, stream>>>(f1T, f2w, f2b, f2T, 2000, 1000);
  fc_t<<<500, 128, 0, stream>>>(f2T, f3w, f3b, f3T, 1000, 500);
  fc_t<<<100, 128, 0, stream>>>(f3T, f4w, f4b, f4T, 500, 100);
  out_lsm<<<1, 128, 0, stream>>>(f4T, ow, ob, out);
}

// Round 5
// 4782.298 us; speedup vs baseline: 1.6731x; 1.0839x over previous
//
#include <hip/hip_runtime.h>
#include <hip/hip_fp16.h>
#include <cstdint>

typedef _Float16 f16;
typedef _Float16 f16x8 __attribute__((ext_vector_type(8)));
typedef float f32x4 __attribute__((ext_vector_type(4)));

#define BATCH 128

// ---------------------------------------------------------------- weight prep
__global__ void pad_w_f16(const float* __restrict__ w, f16* __restrict__ o,
                          int N, int K, int Kp, long total) {
  long idx = (long)blockIdx.x * blockDim.x + threadIdx.x;
  if (idx >= total) return;
  int k = (int)(idx % Kp);
  int n = (int)(idx / Kp);
  float v = (n < N && k < K) ? w[(size_t)n * K + k] : 0.f;
  o[idx] = (f16)v;
}

__global__ void pad_bias(const float* __restrict__ b, float* __restrict__ o, int N, int Np) {
  int i = blockIdx.x * blockDim.x + threadIdx.x;
  if (i < Np) o[i] = (i < N) ? b[i] : 0.f;
}

// conv weight [CO][CI][3][3] -> wp [COp][Kp], k = tap*CI + ci  (tap = ky*3+kx)
__global__ void prep_convw(const float* __restrict__ w, f16* __restrict__ o,
                           int CO, int CI, int COp, int Kp) {
  int idx = blockIdx.x * blockDim.x + threadIdx.x;
  int total = COp * Kp;
  if (idx >= total) return;
  int k = idx % Kp;
  int co = idx / Kp;
  float v = 0.f;
  if (co < CO && k < 9 * CI) {
    int tap = k / CI, ci = k % CI;
    v = w[((size_t)co * CI + ci) * 9 + tap];
  }
  o[idx] = (f16)v;
}

// ---------------------------------------------------------------- im2col
__global__ void im2col1(const float* __restrict__ img, f16* __restrict__ A) {
  int idx = blockIdx.x * blockDim.x + threadIdx.x;
  const int total = 204800 * 32;
  if (idx >= total) return;
  int k = idx & 31;
  int m = idx >> 5;
  int ox = m % 40; int t = m / 40;
  int oy = t % 40; int b = t / 40;
  float v = 0.f;
  if (k < 27) {
    int tap = k / 3, ci = k % 3;
    int iy = oy * 2 - 1 + tap / 3;
    int ix = ox * 2 - 1 + tap % 3;
    if ((unsigned)iy < 80u && (unsigned)ix < 80u)
      v = img[(((size_t)b * 3 + ci) * 80 + iy) * 80 + ix];
  }
  A[idx] = (f16)v;
}

__global__ void im2col_nhwc(const f16* __restrict__ y, f16* __restrict__ A,
                            int H, int W, int OH, int OW, int Cs, int Cv, int Kp,
                            long total) {
  long idx = (long)blockIdx.x * blockDim.x + threadIdx.x;
  if (idx >= total) return;
  int G = Cv >> 3;
  int cg = (int)(idx % G);
  long t = idx / G;
  int tap = (int)(t % 9);
  int m = (int)(t / 9);
  int ox = m % OW; int t2 = m / OW;
  int oy = t2 % OH; int b = t2 / OH;
  int iy = oy * 2 - 1 + tap / 3;
  int ix = ox * 2 - 1 + tap % 3;
  f16x8 v = {};
  if ((unsigned)iy < (unsigned)H && (unsigned)ix < (unsigned)W)
    v = *(const f16x8*)&y[(((size_t)b * H + iy) * W + ix) * Cs + cg * 8];
  *(f16x8*)&A[(size_t)m * Kp + tap * Cv + cg * 8] = v;
}

// ---------------------------------------------------------------- batchnorm (NHWC, two-stage)
__global__ void bn_part(const f16* __restrict__ y, float* __restrict__ psum,
                        float* __restrict__ psq, int M, int Cs, int RPB) {
  int G = Cs >> 3;
  int R = 256 / G;
  int tid = threadIdx.x;
  int g = tid % G, r = tid / G;
  int row0 = blockIdx.x * RPB;
  int rowEnd = row0 + RPB; if (rowEnd > M) rowEnd = M;
  float s[8], q[8];
  #pragma unroll
  for (int e = 0; e < 8; ++e) { s[e] = 0.f; q[e] = 0.f; }
  for (int row = row0 + r; row < rowEnd; row += R) {
    f16x8 v = *(const f16x8*)&y[(size_t)row * Cs + g * 8];
    #pragma unroll
    for (int e = 0; e < 8; ++e) { float f = (float)v[e]; s[e] += f; q[e] += f * f; }
  }
  __shared__ float ls[256 * 8];
  __shared__ float lq[256 * 8];
  #pragma unroll
  for (int e = 0; e < 8; ++e) { ls[tid * 8 + e] = s[e]; lq[tid * 8 + e] = q[e]; }
  __syncthreads();
  for (int st = R / 2; st > 0; st >>= 1) {
    if (r < st) {
      int o = tid * 8, p = (tid + st * G) * 8;
      #pragma unroll
      for (int e = 0; e < 8; ++e) { ls[o + e] += ls[p + e]; lq[o + e] += lq[p + e]; }
    }
    __syncthreads();
  }
  if (r == 0) {
    #pragma unroll
    for (int e = 0; e < 8; ++e) {
      psum[(size_t)blockIdx.x * Cs + g * 8 + e] = ls[tid * 8 + e];
      psq [(size_t)blockIdx.x * Cs + g * 8 + e] = lq[tid * 8 + e];
    }
  }
}

__global__ void bn_final(const float* __restrict__ psum, const float* __restrict__ psq,
                         const float* __restrict__ g, const float* __restrict__ beta,
                         float* __restrict__ scale, float* __restrict__ shift,
                         int nblk, int Cs, int Cv, int M) {
  int c = threadIdx.x;
  if (c >= Cs) return;
  float s = 0.f, q = 0.f;
  for (int b = 0; b < nblk; ++b) { s += psum[(size_t)b * Cs + c]; q += psq[(size_t)b * Cs + c]; }
  float inv = 1.f / (float)M;
  float m = s * inv;
  float var = q * inv - m * m;
  if (c < Cv) {
    float sc = g[c] * rsqrtf(var + 1e-5f);
    scale[c] = sc;
    shift[c] = beta[c] - m * sc;
  } else {
    scale[c] = 0.f;
    shift[c] = 0.f;
  }
}

__global__ void bn_apply(f16* __restrict__ y, const float* __restrict__ scale,
                         const float* __restrict__ shift, long totalGroups, int Cs) {
  long idx = (long)blockIdx.x * blockDim.x + threadIdx.x;
  if (idx >= totalGroups) return;
  int G = Cs >> 3;
  int cg = (int)(idx % G);
  long m = idx / G;
  f16x8 v = *(const f16x8*)&y[m * Cs + cg * 8];
  #pragma unroll
  for (int e = 0; e < 8; ++e)
    v[e] = (f16)((float)v[e] * scale[cg * 8 + e] + shift[cg * 8 + e]);
  *(f16x8*)&y[m * Cs + cg * 8] = v;
}

// ---------------------------------------------------------------- rel build (vectorized, 8 f16/thread)
__global__ void build_rel8(const f16* __restrict__ y4, const float* __restrict__ q,
                           f16* __restrict__ rel, int rowStart, int nRows) {
  long idx = (long)blockIdx.x * blockDim.x + threadIdx.x;
  long total = (long)nRows * 68;
  if (idx >= total) return;
  int kg = (int)(idx % 68);
  long t = idx / 68;
  long grow = rowStart + t;
  int pair = (int)(grow % 625);
  int b = (int)(grow / 625);
  int i = pair / 25, j = pair % 25;
  const f16* yj = y4 + ((size_t)b * 25 + j) * 256;
  const f16* yi = y4 + ((size_t)b * 25 + i) * 256;
  int k0 = kg * 8;
  f16x8 v;
  if (k0 < 256) {
    v = *(const f16x8*)&yj[k0];
  } else if (k0 >= 264 && k0 + 8 <= 514) {
    #pragma unroll
    for (int e = 0; e < 8; ++e) v[e] = yi[k0 + e - 258];
  } else {
    #pragma unroll
    for (int e = 0; e < 8; ++e) {
      int k = k0 + e;
      float f;
      if (k < 256)       f = (float)yj[k];
      else if (k == 256) f = (float)(j / 5) * 0.5f - 1.f;
      else if (k == 257) f = (float)(j % 5) * 0.5f - 1.f;
      else if (k < 514)  f = (float)yi[k - 258];
      else if (k == 514) f = (float)(i / 5) * 0.5f - 1.f;
      else if (k == 515) f = (float)(i % 5) * 0.5f - 1.f;
      else if (k < 527)  f = q[b * 11 + (k - 516)];
      else               f = 0.f;
      v[e] = (f16)f;
    }
  }
  *(f16x8*)&rel[t * 544 + k0] = v;
}

// ---------------------------------------------------------------- fp16 MFMA GEMM (m97 structure + tile swizzle)
__device__ __forceinline__ void load_lds16(const void* g, void* l) {
  __builtin_amdgcn_global_load_lds((const __attribute__((address_space(1))) unsigned int*)g,
                                   (__attribute__((address_space(3))) unsigned int*)l,
                                   16, 0, 0);
}

__global__ __launch_bounds__(256) void gemm_f16(const f16* __restrict__ A,
                                                const f16* __restrict__ Bw,
                                                const float* __restrict__ bias,
                                                f16* __restrict__ C,
                                                int M, int N, int K) {
  __shared__ __align__(16) f16 As[128 * 32];
  __shared__ __align__(16) f16 Bs[128 * 32];
  int tid = threadIdx.x;
  int wv = tid >> 6, l = tid & 63;

  // ---- tile decomposition: bijective XCD swizzle (m204) + GM-grouping ----
  int nBM = M >> 7, nBN = N >> 7;
  int nwg = nBM * nBN;
  int orig = blockIdx.x;
  int qq = nwg >> 3, rr = nwg & 7;
  int xcd = orig & 7;
  int wg = (xcd < rr ? xcd * (qq + 1) : rr * (qq + 1) + (xcd - rr) * qq) + (orig >> 3);
  int GM = (nBM % 5 == 0) ? 5 : (nBM % 4 == 0) ? 4 : (nBM % 2 == 0) ? 2 : 1;
  int per = GM * nBN;
  int grp = wg / per;
  int inn = wg % per;
  int bm = grp * GM + (inn % GM);
  int bn = inn / GM;

  int wm = wv >> 1, wn = wv & 1;
  int lr = l & 15, lk = l >> 4;

  int e0 = (wv * 2) * 64 + l;
  int e1 = e0 + 64;
  int r0 = e0 >> 2, ch0 = e0 & 3;
  int r1 = e1 >> 2, ch1 = e1 & 3;
  const f16* ga0 = A + (size_t)(bm * 128 + r0) * K + ch0 * 8;
  const f16* ga1 = A + (size_t)(bm * 128 + r1) * K + ch1 * 8;
  const f16* gb0 = Bw + (size_t)(bn * 128 + r0) * K + ch0 * 8;
  const f16* gb1 = Bw + (size_t)(bn * 128 + r1) * K + ch1 * 8;
  f16* la0 = As + (wv * 2 + 0) * 512;
  f16* la1 = As + (wv * 2 + 1) * 512;
  f16* lb0 = Bs + (wv * 2 + 0) * 512;
  f16* lb1 = Bs + (wv * 2 + 1) * 512;

  f32x4 zero = {0.f, 0.f, 0.f, 0.f};
  f32x4 acc[4][4];
  #pragma unroll
  for (int i = 0; i < 4; ++i)
    #pragma unroll
    for (int j = 0; j < 4; ++j) acc[i][j] = zero;

  int nk = K >> 5;
  for (int kt = 0; kt < nk; ++kt) {
    __syncthreads();
    load_lds16(ga0, la0);
    load_lds16(ga1, la1);
    load_lds16(gb0, lb0);
    load_lds16(gb1, lb1);
    ga0 += 32; ga1 += 32; gb0 += 32; gb1 += 32;
    __syncthreads();
    f16x8 af[4], bf[4];
    #pragma unroll
    for (int i = 0; i < 4; ++i)
      af[i] = *(const f16x8*)&As[(wm * 64 + i * 16 + lr) * 32 + lk * 8];
    #pragma unroll
    for (int j = 0; j < 4; ++j)
      bf[j] = *(const f16x8*)&Bs[(wn * 64 + j * 16 + lr) * 32 + lk * 8];
    #pragma unroll
    for (int i = 0; i < 4; ++i)
      #pragma unroll
      for (int j = 0; j < 4; ++j)
        acc[i][j] = __builtin_amdgcn_mfma_f32_16x16x32_f16(af[i], bf[j], acc[i][j], 0, 0, 0);
  }

  int crow = bm * 128 + wm * 64;
  int ccol = bn * 128 + wn * 64;
  #pragma unroll
  for (int j = 0; j < 4; ++j) {
    int col = ccol + j * 16 + lr;
    float bj = bias[col];
    #pragma unroll
    for (int i = 0; i < 4; ++i) {
      int rowb = crow + i * 16 + lk * 4;
      #pragma unroll
      for (int r = 0; r < 4; ++r) {
        float v = acc[i][j][r] + bj;
        v = fmaxf(v, 0.f);
        C[(size_t)(rowb + r) * N + col] = (f16)v;
      }
    }
  }
}

// ---------------------------------------------------------------- pair sum (vectorized)
__global__ void pair_sum8(const f16* __restrict__ h4, float* __restrict__ hsumT,
                          int rowStart, int nRows, int gb0) {
  int b = gb0 + blockIdx.x;
  if (b >= BATCH) return;
  int r0 = b * 625 - rowStart;       if (r0 < 0) r0 = 0;
  int r1 = (b + 1) * 625 - rowStart; if (r1 > nRows) r1 = nRows;
  if (r0 >= r1) return;
  int cg = threadIdx.x;   // 256 col-groups of 8
  float acc[8];
  #pragma unroll
  for (int e = 0; e < 8; ++e) acc[e] = 0.f;
  for (int r = r0; r < r1; ++r) {
    f16x8 v = *(const f16x8*)&h4[(size_t)r * 2048 + cg * 8];
    #pragma unroll
    for (int e = 0; e < 8; ++e) acc[e] += (float)v[e];
  }
  #pragma unroll
  for (int e = 0; e < 8; ++e)
    hsumT[(size_t)(cg * 8 + e) * BATCH + b] += acc[e];
}

// ---------------------------------------------------------------- fp32 FC (transposed act)
__global__ void fc_t(const float* __restrict__ inT, const float* __restrict__ w,
                     const float* __restrict__ bias, float* __restrict__ outT,
                     int K, int N) {
  int n = blockIdx.x;
  int m = threadIdx.x;
  const float* wr = w + (size_t)n * K;
  float acc = bias[n];
  int k = 0;
  for (; k + 4 <= K; k += 4) {
    acc += inT[(size_t)(k + 0) * BATCH + m] * wr[k + 0]
         + inT[(size_t)(k + 1) * BATCH + m] * wr[k + 1]
         + inT[(size_t)(k + 2) * BATCH + m] * wr[k + 2]
         + inT[(size_t)(k + 3) * BATCH + m] * wr[k + 3];
  }
  for (; k < K; ++k) acc += inT[(size_t)k * BATCH + m] * wr[k];
  outT[(size_t)n * BATCH + m] = fmaxf(acc, 0.f);
}

// ---------------------------------------------------------------- final linear + log_softmax
__global__ void out_lsm(const float* __restrict__ f4T, const float* __restrict__ ow,
                        const float* __restrict__ ob, float* __restrict__ out) {
  int m = threadIdx.x;
  float z[10];
  #pragma unroll
  for (int c = 0; c < 10; ++c) {
    float acc = ob[c];
    for (int k = 0; k < 100; ++k) acc += f4T[(size_t)k * BATCH + m] * ow[c * 100 + k];
    z[c] = fmaxf(acc, 0.f);
  }
  float mx = z[0];
  #pragma unroll
  for (int c = 1; c < 10; ++c) mx = fmaxf(mx, z[c]);
  float s = 0.f;
  #pragma unroll
  for (int c = 0; c < 10; ++c) s += expf(z[c] - mx);
  float lse = mx + logf(s);
  #pragma unroll
  for (int c = 0; c < 10; ++c) out[m * 10 + c] = z[c] - lse;
}

// ---------------------------------------------------------------- host
extern "C" void kernel_launch(void* const* d_in, const int* in_sizes, int n_in,
                              void* d_out, int out_size, void* d_ws, size_t ws_size,
                              hipStream_t stream) {
  const float* image = (const float*)d_in[0];
  const float* questions = (const float*)d_in[1];
  const float* c1w = (const float*)d_in[2];  const float* c1b = (const float*)d_in[3];
  const float* bn1g = (const float*)d_in[4]; const float* bn1b = (const float*)d_in[5];
  const float* c2w = (const float*)d_in[6];  const float* c2b = (const float*)d_in[7];
  const float* bn2g = (const float*)d_in[8]; const float* bn2b = (const float*)d_in[9];
  const float* c3w = (const float*)d_in[10]; const float* c3b = (const float*)d_in[11];
  const float* bn3g = (const float*)d_in[12];const float* bn3b = (const float*)d_in[13];
  const float* c4w = (const float*)d_in[14]; const float* c4b = (const float*)d_in[15];
  const float* bn4g = (const float*)d_in[16];const float* bn4b = (const float*)d_in[17];
  const float* g1w = (const float*)d_in[18]; const float* g1b = (const float*)d_in[19];
  const float* g2w = (const float*)d_in[20]; const float* g2b = (const float*)d_in[21];
  const float* g3w = (const float*)d_in[22]; const float* g3b = (const float*)d_in[23];
  const float* g4w = (const float*)d_in[24]; const float* g4b = (const float*)d_in[25];
  const float* f1w = (const float*)d_in[26]; const float* f1b = (const float*)d_in[27];
  const float* f2w = (const float*)d_in[28]; const float* f2b = (const float*)d_in[29];
  const float* f3w = (const float*)d_in[30]; const float* f3b = (const float*)d_in[31];
  const float* f4w = (const float*)d_in[32]; const float* f4b = (const float*)d_in[33];
  const float* ow  = (const float*)d_in[34]; const float* ob  = (const float*)d_in[35];
  float* out = (float*)d_out;
  (void)in_sizes; (void)n_in; (void)out_size;

  // ---------------- workspace sizing ----
  const size_t MB = 1024ull * 1024;
  const size_t PERSIST =
      2048ull * 544 * 2 + 3ull * 2048 * 2048 * 2 +
      4ull * 2048 * 4 +
      (128ull * 32 + 128 * 288 + 128 * 576 + 256 * 1152) * 2 +
      (128ull + 128 + 128 + 256) * 4 +
      2ull * 205 * 256 * 4 +
      2ull * 256 * 4 +
      3200ull * 256 * 2 +
      2048ull * BATCH * 4 +
      (2000ull + 1000 + 500 + 100) * BATCH * 4 +
      64ull * 256;

  auto need = [&](int CH) -> size_t {
    size_t sg = (size_t)CH * 4096;
    size_t SA = sg > 56 * MB ? sg : 56 * MB;
    size_t SB = sg > 30 * MB ? sg : 30 * MB;
    size_t sc = (size_t)CH * 1088;
    size_t SC = sc > 14 * MB ? sc : 14 * MB;
    return PERSIST + SA + SB + SC;
  };
  int CH = 1024;
  const int cands[4] = {16000, 8192, 4096, 2048};
  for (int ci = 0; ci < 4; ++ci)
    if (need(cands[ci]) <= ws_size) { CH = cands[ci]; break; }

  char* ws = (char*)d_ws;
  size_t off = 0;
  auto alloc = [&](size_t bytes) -> void* {
    void* p = ws + off;
    off += (bytes + 255) & ~(size_t)255;
    return p;
  };
  f16* wg1 = (f16*)alloc(2048ull * 544 * 2);
  f16* wg2 = (f16*)alloc(2048ull * 2048 * 2);
  f16* wg3 = (f16*)alloc(2048ull * 2048 * 2);
  f16* wg4 = (f16*)alloc(2048ull * 2048 * 2);
  float* bgp = (float*)alloc(4 * 2048 * 4);
  f16* wp1 = (f16*)alloc(128ull * 32 * 2);
  f16* wp2 = (f16*)alloc(128ull * 288 * 2);
  f16* wp3 = (f16*)alloc(128ull * 576 * 2);
  f16* wp4 = (f16*)alloc(256ull * 1152 * 2);
  float* bc1p = (float*)alloc(128 * 4);
  float* bc2p = (float*)alloc(128 * 4);
  float* bc3p = (float*)alloc(128 * 4);
  float* bc4p = (float*)alloc(256 * 4);
  float* psum = (float*)alloc(205ull * 256 * 4);
  float* psq  = (float*)alloc(205ull * 256 * 4);
  float* scl  = (float*)alloc(256 * 4);
  float* shf  = (float*)alloc(256 * 4);
  f16* y4 = (f16*)alloc(3200ull * 256 * 2);
  float* hsumT = (float*)alloc(2048ull * BATCH * 4);
  float* f1T = (float*)alloc(2000ull * BATCH * 4);
  float* f2T = (float*)alloc(1000ull * BATCH * 4);
  float* f3T = (float*)alloc(500ull * BATCH * 4);
  float* f4T = (float*)alloc(100ull * BATCH * 4);

  size_t sg = (size_t)CH * 4096;
  size_t SA = sg > 56 * MB ? sg : 56 * MB;
  size_t SB = sg > 30 * MB ? sg : 30 * MB;
  size_t sc = (size_t)CH * 1088;
  size_t SC = sc > 14 * MB ? sc : 14 * MB;
  char* regA = (char*)alloc(SA);
  char* regB = (char*)alloc(SB);
  char* regC = (char*)alloc(SC);

  f16* y1 = (f16*)regA;
  f16* A1 = (f16*)regB;
  f16* A2 = (f16*)regB;
  f16* y2 = (f16*)regC;
  f16* A3 = (f16*)regA;
  f16* y3 = (f16*)regB;
  f16* A4 = (f16*)(regB + 4 * MB);
  f16* hA = (f16*)regA;
  f16* hB = (f16*)regB;
  f16* relc = (f16*)regC;

  // ---- weight prep ----
  {
    long t1 = 2048L * 544;
    pad_w_f16<<<(int)((t1 + 255) / 256), 256, 0, stream>>>(g1w, wg1, 2000, 527, 544, t1);
    long t2 = 2048L * 2048;
    pad_w_f16<<<(int)((t2 + 255) / 256), 256, 0, stream>>>(g2w, wg2, 2000, 2000, 2048, t2);
    pad_w_f16<<<(int)((t2 + 255) / 256), 256, 0, stream>>>(g3w, wg3, 2000, 2000, 2048, t2);
    pad_w_f16<<<(int)((t2 + 255) / 256), 256, 0, stream>>>(g4w, wg4, 2000, 2000, 2048, t2);
    pad_bias<<<8, 256, 0, stream>>>(g1b, bgp + 0 * 2048, 2000, 2048);
    pad_bias<<<8, 256, 0, stream>>>(g2b, bgp + 1 * 2048, 2000, 2048);
    pad_bias<<<8, 256, 0, stream>>>(g3b, bgp + 2 * 2048, 2000, 2048);
    pad_bias<<<8, 256, 0, stream>>>(g4b, bgp + 3 * 2048, 2000, 2048);
    prep_convw<<<(128 * 32 + 255) / 256, 256, 0, stream>>>(c1w, wp1, 32, 3, 128, 32);
    prep_convw<<<(128 * 288 + 255) / 256, 256, 0, stream>>>(c2w, wp2, 64, 32, 128, 288);
    prep_convw<<<(128 * 576 + 255) / 256, 256, 0, stream>>>(c3w, wp3, 128, 64, 128, 576);
    prep_convw<<<(256 * 1152 + 255) / 256, 256, 0, stream>>>(c4w, wp4, 256, 128, 256, 1152);
    pad_bias<<<1, 256, 0, stream>>>(c1b, bc1p, 32, 128);
    pad_bias<<<1, 256, 0, stream>>>(c2b, bc2p, 64, 128);
    pad_bias<<<1, 256, 0, stream>>>(c3b, bc3p, 128, 128);
    pad_bias<<<1, 256, 0, stream>>>(c4b, bc4p, 256, 256);
  }

  // ---- conv stack: im2col + gemm + BN, NHWC f16 ----
  im2col1<<<(204800 * 32 + 255) / 256, 256, 0, stream>>>(image, A1);
  gemm_f16<<<1600, 256, 0, stream>>>(A1, wp1, bc1p, y1, 204800, 128, 32);
  bn_part<<<200, 256, 0, stream>>>(y1, psum, psq, 204800, 128, 1024);
  bn_final<<<1, 256, 0, stream>>>(psum, psq, bn1g, bn1b, scl, shf, 200, 128, 32, 204800);
  bn_apply<<<(int)((204800L * 16 + 255) / 256), 256, 0, stream>>>(y1, scl, shf, 204800L * 16, 128);
  { long t = 51200L * 9 * 4;
    im2col_nhwc<<<(int)((t + 255) / 256), 256, 0, stream>>>(y1, A2, 40, 40, 20, 20, 128, 32, 288, t); }
  gemm_f16<<<400, 256, 0, stream>>>(A2, wp2, bc2p, y2, 51200, 128, 288);
  bn_part<<<50, 256, 0, stream>>>(y2, psum, psq, 51200, 128, 1024);
  bn_final<<<1, 256, 0, stream>>>(psum, psq, bn2g, bn2b, scl, shf, 50, 128, 64, 51200);
  bn_apply<<<(int)((51200L * 16 + 255) / 256), 256, 0, stream>>>(y2, scl, shf, 51200L * 16, 128);
  { long t = 12800L * 9 * 8;
    im2col_nhwc<<<(int)((t + 255) / 256), 256, 0, stream>>>(y2, A3, 20, 20, 10, 10, 128, 64, 576, t); }
  gemm_f16<<<100, 256, 0, stream>>>(A3, wp3, bc3p, y3, 12800, 128, 576);
  bn_part<<<13, 256, 0, stream>>>(y3, psum, psq, 12800, 128, 1024);
  bn_final<<<1, 256, 0, stream>>>(psum, psq, bn3g, bn3b, scl, shf, 13, 128, 128, 12800);
  bn_apply<<<(int)((12800L * 16 + 255) / 256), 256, 0, stream>>>(y3, scl, shf, 12800L * 16, 128);
  { long t = 3200L * 9 * 16;
    im2col_nhwc<<<(int)((t + 255) / 256), 256, 0, stream>>>(y3, A4, 10, 10, 5, 5, 128, 128, 1152, t); }
  gemm_f16<<<50, 256, 0, stream>>>(A4, wp4, bc4p, y4, 3200, 256, 1152);
  bn_part<<<4, 256, 0, stream>>>(y4, psum, psq, 3200, 256, 1024);
  bn_final<<<1, 256, 0, stream>>>(psum, psq, bn4g, bn4b, scl, shf, 4, 256, 256, 3200);
  bn_apply<<<(int)((3200L * 32 + 255) / 256), 256, 0, stream>>>(y4, scl, shf, 3200L * 32, 256);

  // ---- g-MLP (chunked) + pair sum ----
  hipMemsetAsync(hsumT, 0, 2048ull * BATCH * 4, stream);
  for (int start = 0; start < 80000; start += CH) {
    int M = 80000 - start;
    if (M > CH) M = CH;
    long tr = (long)M * 68;
    build_rel8<<<(int)((tr + 255) / 256), 256, 0, stream>>>(y4, questions, relc, start, M);
    int ng = (M / 128) * 16;
    gemm_f16<<<ng, 256, 0, stream>>>(relc, wg1, bgp + 0 * 2048, hA, M, 2048, 544);
    gemm_f16<<<ng, 256, 0, stream>>>(hA, wg2, bgp + 1 * 2048, hB, M, 2048, 2048);
    gemm_f16<<<ng, 256, 0, stream>>>(hB, wg3, bgp + 2 * 2048, hA, M, 2048, 2048);
    gemm_f16<<<ng, 256, 0, stream>>>(hA, wg4, bgp + 3 * 2048, hB, M, 2048, 2048);
    int gb0 = start / 625;
    int gb1 = (start + M - 1) / 625;
    pair_sum8<<<gb1 - gb0 + 1, 256, 0, stream>>>(hB, hsumT, start, M, gb0);
  }

  // ---- f-MLP ----
  fc_t<<<2000, 128, 0, stream>>>(hsumT, f1w, f1b, f1T, 2000, 2000);
  fc_t<<<1000, 128, 0, stream>>>(f1T, f2w, f2b, f2T, 2000, 1000);
  fc_t<<<500, 128, 0, stream>>>(f2T, f3w, f3b, f3T, 1000, 500);
  fc_t<<<100, 128, 0, stream>>>(f3T, f4w, f4b, f4T, 500, 100);
  out_lsm<<<1, 128, 0, stream>>>(f4T, ow, ob, out);
}

// Round 6
// 3530.155 us; speedup vs baseline: 2.2666x; 1.3547x over previous
//
#include <hip/hip_runtime.h>
#include <hip/hip_fp16.h>
#include <cstdint>

typedef _Float16 f16;
typedef _Float16 f16x8 __attribute__((ext_vector_type(8)));
typedef float f32x4 __attribute__((ext_vector_type(4)));

#define BATCH 128

// ---------------------------------------------------------------- weight prep
__global__ void pad_w_f16(const float* __restrict__ w, f16* __restrict__ o,
                          int N, int K, int Kp, long total) {
  long idx = (long)blockIdx.x * blockDim.x + threadIdx.x;
  if (idx >= total) return;
  int k = (int)(idx % Kp);
  int n = (int)(idx / Kp);
  float v = (n < N && k < K) ? w[(size_t)n * K + k] : 0.f;
  o[idx] = (f16)v;
}

__global__ void pad_bias(const float* __restrict__ b, float* __restrict__ o, int N, int Np) {
  int i = blockIdx.x * blockDim.x + threadIdx.x;
  if (i < Np) o[i] = (i < N) ? b[i] : 0.f;
}

__global__ void prep_convw(const float* __restrict__ w, f16* __restrict__ o,
                           int CO, int CI, int COp, int Kp) {
  int idx = blockIdx.x * blockDim.x + threadIdx.x;
  int total = COp * Kp;
  if (idx >= total) return;
  int k = idx % Kp;
  int co = idx / Kp;
  float v = 0.f;
  if (co < CO && k < 9 * CI) {
    int tap = k / CI, ci = k % CI;
    v = w[((size_t)co * CI + ci) * 9 + tap];
  }
  o[idx] = (f16)v;
}

// ---------------------------------------------------------------- im2col
__global__ void im2col1(const float* __restrict__ img, f16* __restrict__ A) {
  int idx = blockIdx.x * blockDim.x + threadIdx.x;
  const int total = 204800 * 32;
  if (idx >= total) return;
  int k = idx & 31;
  int m = idx >> 5;
  int ox = m % 40; int t = m / 40;
  int oy = t % 40; int b = t / 40;
  float v = 0.f;
  if (k < 27) {
    int tap = k / 3, ci = k % 3;
    int iy = oy * 2 - 1 + tap / 3;
    int ix = ox * 2 - 1 + tap % 3;
    if ((unsigned)iy < 80u && (unsigned)ix < 80u)
      v = img[(((size_t)b * 3 + ci) * 80 + iy) * 80 + ix];
  }
  A[idx] = (f16)v;
}

__global__ void im2col_nhwc(const f16* __restrict__ y, f16* __restrict__ A,
                            int H, int W, int OH, int OW, int Cs, int Cv, int Kp,
                            long total) {
  long idx = (long)blockIdx.x * blockDim.x + threadIdx.x;
  if (idx >= total) return;
  int G = Cv >> 3;
  int cg = (int)(idx % G);
  long t = idx / G;
  int tap = (int)(t % 9);
  int m = (int)(t / 9);
  int ox = m % OW; int t2 = m / OW;
  int oy = t2 % OH; int b = t2 / OH;
  int iy = oy * 2 - 1 + tap / 3;
  int ix = ox * 2 - 1 + tap % 3;
  f16x8 v = {};
  if ((unsigned)iy < (unsigned)H && (unsigned)ix < (unsigned)W)
    v = *(const f16x8*)&y[(((size_t)b * H + iy) * W + ix) * Cs + cg * 8];
  *(f16x8*)&A[(size_t)m * Kp + tap * Cv + cg * 8] = v;
}

// ---------------------------------------------------------------- batchnorm (NHWC, two-stage)
__global__ void bn_part(const f16* __restrict__ y, float* __restrict__ psum,
                        float* __restrict__ psq, int M, int Cs, int RPB) {
  int G = Cs >> 3;
  int R = 256 / G;
  int tid = threadIdx.x;
  int g = tid % G, r = tid / G;
  int row0 = blockIdx.x * RPB;
  int rowEnd = row0 + RPB; if (rowEnd > M) rowEnd = M;
  float s[8], q[8];
  #pragma unroll
  for (int e = 0; e < 8; ++e) { s[e] = 0.f; q[e] = 0.f; }
  for (int row = row0 + r; row < rowEnd; row += R) {
    f16x8 v = *(const f16x8*)&y[(size_t)row * Cs + g * 8];
    #pragma unroll
    for (int e = 0; e < 8; ++e) { float f = (float)v[e]; s[e] += f; q[e] += f * f; }
  }
  __shared__ float ls[256 * 8];
  __shared__ float lq[256 * 8];
  #pragma unroll
  for (int e = 0; e < 8; ++e) { ls[tid * 8 + e] = s[e]; lq[tid * 8 + e] = q[e]; }
  __syncthreads();
  for (int st = R / 2; st > 0; st >>= 1) {
    if (r < st) {
      int o = tid * 8, p = (tid + st * G) * 8;
      #pragma unroll
      for (int e = 0; e < 8; ++e) { ls[o + e] += ls[p + e]; lq[o + e] += lq[p + e]; }
    }
    __syncthreads();
  }
  if (r == 0) {
    #pragma unroll
    for (int e = 0; e < 8; ++e) {
      psum[(size_t)blockIdx.x * Cs + g * 8 + e] = ls[tid * 8 + e];
      psq [(size_t)blockIdx.x * Cs + g * 8 + e] = lq[tid * 8 + e];
    }
  }
}

__global__ void bn_final(const float* __restrict__ psum, const float* __restrict__ psq,
                         const float* __restrict__ g, const float* __restrict__ beta,
                         float* __restrict__ scale, float* __restrict__ shift,
                         int nblk, int Cs, int Cv, int M) {
  int c = threadIdx.x;
  if (c >= Cs) return;
  float s = 0.f, q = 0.f;
  for (int b = 0; b < nblk; ++b) { s += psum[(size_t)b * Cs + c]; q += psq[(size_t)b * Cs + c]; }
  float inv = 1.f / (float)M;
  float m = s * inv;
  float var = q * inv - m * m;
  if (c < Cv) {
    float sc = g[c] * rsqrtf(var + 1e-5f);
    scale[c] = sc;
    shift[c] = beta[c] - m * sc;
  } else {
    scale[c] = 0.f;
    shift[c] = 0.f;
  }
}

__global__ void bn_apply(f16* __restrict__ y, const float* __restrict__ scale,
                         const float* __restrict__ shift, long totalGroups, int Cs) {
  long idx = (long)blockIdx.x * blockDim.x + threadIdx.x;
  if (idx >= totalGroups) return;
  int G = Cs >> 3;
  int cg = (int)(idx % G);
  long m = idx / G;
  f16x8 v = *(const f16x8*)&y[m * Cs + cg * 8];
  #pragma unroll
  for (int e = 0; e < 8; ++e)
    v[e] = (f16)((float)v[e] * scale[cg * 8 + e] + shift[cg * 8 + e]);
  *(f16x8*)&y[m * Cs + cg * 8] = v;
}

// ---------------------------------------------------------------- rel build (stride 640, zero-padded)
__global__ void build_rel8(const f16* __restrict__ y4, const float* __restrict__ q,
                           f16* __restrict__ rel, int rowStart, int nRowsPad) {
  long idx = (long)blockIdx.x * blockDim.x + threadIdx.x;
  long total = (long)nRowsPad * 80;
  if (idx >= total) return;
  int kg = (int)(idx % 80);
  long t = idx / 80;
  long grow = rowStart + t;
  int k0 = kg * 8;
  f16x8 v = {};
  if (grow < 80000) {
    int pair = (int)(grow % 625);
    int b = (int)(grow / 625);
    int i = pair / 25, j = pair % 25;
    const f16* yj = y4 + ((size_t)b * 25 + j) * 256;
    const f16* yi = y4 + ((size_t)b * 25 + i) * 256;
    if (k0 < 256) {
      v = *(const f16x8*)&yj[k0];
    } else if (k0 >= 264 && k0 + 8 <= 514) {
      #pragma unroll
      for (int e = 0; e < 8; ++e) v[e] = yi[k0 + e - 258];
    } else if (k0 < 528) {
      #pragma unroll
      for (int e = 0; e < 8; ++e) {
        int k = k0 + e;
        float f;
        if (k < 256)       f = (float)yj[k];
        else if (k == 256) f = (float)(j / 5) * 0.5f - 1.f;
        else if (k == 257) f = (float)(j % 5) * 0.5f - 1.f;
        else if (k < 514)  f = (float)yi[k - 258];
        else if (k == 514) f = (float)(i / 5) * 0.5f - 1.f;
        else if (k == 515) f = (float)(i % 5) * 0.5f - 1.f;
        else if (k < 527)  f = q[b * 11 + (k - 516)];
        else               f = 0.f;
        v[e] = (f16)f;
      }
    }
  }
  *(f16x8*)&rel[t * 640 + k0] = v;
}

// ---------------------------------------------------------------- async global->LDS helper
__device__ __forceinline__ void load_lds16(const void* g, void* l) {
  __builtin_amdgcn_global_load_lds((const __attribute__((address_space(1))) unsigned int*)g,
                                   (__attribute__((address_space(3))) unsigned int*)l,
                                   16, 0, 0);
}

// ---------------------------------------------------------------- fp16 MFMA GEMM 128^2 (m97 structure) — conv layers
__global__ __launch_bounds__(256) void gemm_f16(const f16* __restrict__ A,
                                                const f16* __restrict__ Bw,
                                                const float* __restrict__ bias,
                                                f16* __restrict__ C,
                                                int M, int N, int K) {
  __shared__ __align__(16) f16 As[128 * 32];
  __shared__ __align__(16) f16 Bs[128 * 32];
  int tid = threadIdx.x;
  int wv = tid >> 6, l = tid & 63;

  int nBM = M >> 7, nBN = N >> 7;
  int nwg = nBM * nBN;
  int orig = blockIdx.x;
  int qq = nwg >> 3, rr = nwg & 7;
  int xcd = orig & 7;
  int wg = (xcd < rr ? xcd * (qq + 1) : rr * (qq + 1) + (xcd - rr) * qq) + (orig >> 3);
  int GM = (nBM % 5 == 0) ? 5 : (nBM % 4 == 0) ? 4 : (nBM % 2 == 0) ? 2 : 1;
  int per = GM * nBN;
  int grp = wg / per;
  int inn = wg % per;
  int bm = grp * GM + (inn % GM);
  int bn = inn / GM;

  int wm = wv >> 1, wn = wv & 1;
  int lr = l & 15, lk = l >> 4;

  int e0 = (wv * 2) * 64 + l;
  int e1 = e0 + 64;
  int r0 = e0 >> 2, ch0 = e0 & 3;
  int r1 = e1 >> 2, ch1 = e1 & 3;
  const f16* ga0 = A + (size_t)(bm * 128 + r0) * K + ch0 * 8;
  const f16* ga1 = A + (size_t)(bm * 128 + r1) * K + ch1 * 8;
  const f16* gb0 = Bw + (size_t)(bn * 128 + r0) * K + ch0 * 8;
  const f16* gb1 = Bw + (size_t)(bn * 128 + r1) * K + ch1 * 8;
  f16* la0 = As + (wv * 2 + 0) * 512;
  f16* la1 = As + (wv * 2 + 1) * 512;
  f16* lb0 = Bs + (wv * 2 + 0) * 512;
  f16* lb1 = Bs + (wv * 2 + 1) * 512;

  f32x4 zero = {0.f, 0.f, 0.f, 0.f};
  f32x4 acc[4][4];
  #pragma unroll
  for (int i = 0; i < 4; ++i)
    #pragma unroll
    for (int j = 0; j < 4; ++j) acc[i][j] = zero;

  int nk = K >> 5;
  for (int kt = 0; kt < nk; ++kt) {
    __syncthreads();
    load_lds16(ga0, la0);
    load_lds16(ga1, la1);
    load_lds16(gb0, lb0);
    load_lds16(gb1, lb1);
    ga0 += 32; ga1 += 32; gb0 += 32; gb1 += 32;
    __syncthreads();
    f16x8 af[4], bf[4];
    #pragma unroll
    for (int i = 0; i < 4; ++i)
      af[i] = *(const f16x8*)&As[(wm * 64 + i * 16 + lr) * 32 + lk * 8];
    #pragma unroll
    for (int j = 0; j < 4; ++j)
      bf[j] = *(const f16x8*)&Bs[(wn * 64 + j * 16 + lr) * 32 + lk * 8];
    #pragma unroll
    for (int i = 0; i < 4; ++i)
      #pragma unroll
      for (int j = 0; j < 4; ++j)
        acc[i][j] = __builtin_amdgcn_mfma_f32_16x16x32_f16(af[i], bf[j], acc[i][j], 0, 0, 0);
  }

  int crow = bm * 128 + wm * 64;
  int ccol = bn * 128 + wn * 64;
  #pragma unroll
  for (int j = 0; j < 4; ++j) {
    int col = ccol + j * 16 + lr;
    float bj = bias[col];
    #pragma unroll
    for (int i = 0; i < 4; ++i) {
      int rowb = crow + i * 16 + lk * 4;
      #pragma unroll
      for (int r = 0; r < 4; ++r) {
        float v = acc[i][j][r] + bj;
        v = fmaxf(v, 0.f);
        C[(size_t)(rowb + r) * N + col] = (f16)v;
      }
    }
  }
}

// ---------------------------------------------------------------- fp16 MFMA GEMM 256^2, BK=64, 8-phase pipeline
// Requires M%256==0, N%256==0, K%128==0 (nt even >=2).
#define DSREAD_A(BUF, RH) do { \
  a[0][0] = *(const f16x8*)(lds + ((BUF) << 15) + aaddr[(RH)*4 + 0]); \
  a[0][1] = *(const f16x8*)(lds + ((BUF) << 15) + aaddr[(RH)*4 + 0] + 64); \
  a[1][0] = *(const f16x8*)(lds + ((BUF) << 15) + aaddr[(RH)*4 + 1]); \
  a[1][1] = *(const f16x8*)(lds + ((BUF) << 15) + aaddr[(RH)*4 + 1] + 64); \
  a[2][0] = *(const f16x8*)(lds + ((BUF) << 15) + aaddr[(RH)*4 + 2]); \
  a[2][1] = *(const f16x8*)(lds + ((BUF) << 15) + aaddr[(RH)*4 + 2] + 64); \
  a[3][0] = *(const f16x8*)(lds + ((BUF) << 15) + aaddr[(RH)*4 + 3]); \
  a[3][1] = *(const f16x8*)(lds + ((BUF) << 15) + aaddr[(RH)*4 + 3] + 64); \
} while (0)

#define DSREAD_B(BUF, CH) do { \
  b[CH][0][0] = *(const f16x8*)(lds + ((BUF) << 15) + baddr[(CH)*2 + 0]); \
  b[CH][0][1] = *(const f16x8*)(lds + ((BUF) << 15) + baddr[(CH)*2 + 0] + 64); \
  b[CH][1][0] = *(const f16x8*)(lds + ((BUF) << 15) + baddr[(CH)*2 + 1]); \
  b[CH][1][1] = *(const f16x8*)(lds + ((BUF) << 15) + baddr[(CH)*2 + 1] + 64); \
} while (0)

#define MFMA16(RH, CH) do { \
  acc[(RH)*4+0][(CH)*2+0] = __builtin_amdgcn_mfma_f32_16x16x32_f16(a[0][0], b[CH][0][0], acc[(RH)*4+0][(CH)*2+0], 0,0,0); \
  acc[(RH)*4+0][(CH)*2+0] = __builtin_amdgcn_mfma_f32_16x16x32_f16(a[0][1], b[CH][0][1], acc[(RH)*4+0][(CH)*2+0], 0,0,0); \
  acc[(RH)*4+0][(CH)*2+1] = __builtin_amdgcn_mfma_f32_16x16x32_f16(a[0][0], b[CH][1][0], acc[(RH)*4+0][(CH)*2+1], 0,0,0); \
  acc[(RH)*4+0][(CH)*2+1] = __builtin_amdgcn_mfma_f32_16x16x32_f16(a[0][1], b[CH][1][1], acc[(RH)*4+0][(CH)*2+1], 0,0,0); \
  acc[(RH)*4+1][(CH)*2+0] = __builtin_amdgcn_mfma_f32_16x16x32_f16(a[1][0], b[CH][0][0], acc[(RH)*4+1][(CH)*2+0], 0,0,0); \
  acc[(RH)*4+1][(CH)*2+0] = __builtin_amdgcn_mfma_f32_16x16x32_f16(a[1][1], b[CH][0][1], acc[(RH)*4+1][(CH)*2+0], 0,0,0); \
  acc[(RH)*4+1][(CH)*2+1] = __builtin_amdgcn_mfma_f32_16x16x32_f16(a[1][0], b[CH][1][0], acc[(RH)*4+1][(CH)*2+1], 0,0,0); \
  acc[(RH)*4+1][(CH)*2+1] = __builtin_amdgcn_mfma_f32_16x16x32_f16(a[1][1], b[CH][1][1], acc[(RH)*4+1][(CH)*2+1], 0,0,0); \
  acc[(RH)*4+2][(CH)*2+0] = __builtin_amdgcn_mfma_f32_16x16x32_f16(a[2][0], b[CH][0][0], acc[(RH)*4+2][(CH)*2+0], 0,0,0); \
  acc[(RH)*4+2][(CH)*2+0] = __builtin_amdgcn_mfma_f32_16x16x32_f16(a[2][1], b[CH][0][1], acc[(RH)*4+2][(CH)*2+0], 0,0,0); \
  acc[(RH)*4+2][(CH)*2+1] = __builtin_amdgcn_mfma_f32_16x16x32_f16(a[2][0], b[CH][1][0], acc[(RH)*4+2][(CH)*2+1], 0,0,0); \
  acc[(RH)*4+2][(CH)*2+1] = __builtin_amdgcn_mfma_f32_16x16x32_f16(a[2][1], b[CH][1][1], acc[(RH)*4+2][(CH)*2+1], 0,0,0); \
  acc[(RH)*4+3][(CH)*2+0] = __builtin_amdgcn_mfma_f32_16x16x32_f16(a[3][0], b[CH][0][0], acc[(RH)*4+3][(CH)*2+0], 0,0,0); \
  acc[(RH)*4+3][(CH)*2+0] = __builtin_amdgcn_mfma_f32_16x16x32_f16(a[3][1], b[CH][0][1], acc[(RH)*4+3][(CH)*2+0], 0,0,0); \
  acc[(RH)*4+3][(CH)*2+1] = __builtin_amdgcn_mfma_f32_16x16x32_f16(a[3][0], b[CH][1][0], acc[(RH)*4+3][(CH)*2+1], 0,0,0); \
  acc[(RH)*4+3][(CH)*2+1] = __builtin_amdgcn_mfma_f32_16x16x32_f16(a[3][1], b[CH][1][1], acc[(RH)*4+3][(CH)*2+1], 0,0,0); \
} while (0)

#define PHTAIL(RH, CH, VM) do { \
  __builtin_amdgcn_s_barrier(); \
  asm volatile("s_waitcnt lgkmcnt(0)" ::: "memory"); \
  __builtin_amdgcn_sched_barrier(0); \
  __builtin_amdgcn_s_setprio(1); \
  MFMA16(RH, CH); \
  __builtin_amdgcn_s_setprio(0); \
  __builtin_amdgcn_sched_barrier(0); \
  if (VM) { asm volatile("s_waitcnt vmcnt(4)" ::: "memory"); } \
  __builtin_amdgcn_s_barrier(); \
} while (0)

#define STG_A(T, H) do { int t_ = (T); if (t_ < nt) { int lb = ((t_ & 1) << 15) + ((H) << 14); \
  load_lds16(A  + aoff0 + (size_t)(H) * halfA + (size_t)t_ * 64, lds + lb + sdo0); \
  load_lds16(A  + aoff1 + (size_t)(H) * halfA + (size_t)t_ * 64, lds + lb + sdo1); } } while (0)

#define STG_B(T, H) do { int t_ = (T); if (t_ < nt) { int lb = 65536 + ((t_ & 1) << 15) + ((H) << 14); \
  load_lds16(Bw + boff0 + (size_t)(H) * halfA + (size_t)t_ * 64, lds + lb + sdo0); \
  load_lds16(Bw + boff1 + (size_t)(H) * halfA + (size_t)t_ * 64, lds + lb + sdo1); } } while (0)

__global__ __launch_bounds__(512, 1) void gemm256(const f16* __restrict__ A,
                                                  const f16* __restrict__ Bw,
                                                  const float* __restrict__ bias,
                                                  f16* __restrict__ C,
                                                  int M, int N, int K) {
  __shared__ char lds[131072];
  const int tid = threadIdx.x;
  const int w = tid >> 6, l = tid & 63;
  const int lr = l & 15, lk = l >> 4;
  const int nt = K >> 6;

  // tile swizzle (bijective XCD + GM grouping)
  int nBM = M >> 8, nBN = N >> 8;
  int nwg = nBM * nBN;
  int orig = blockIdx.x;
  int qq = nwg >> 3, rr = nwg & 7;
  int xcd = orig & 7;
  int wg = (xcd < rr ? xcd * (qq + 1) : rr * (qq + 1) + (xcd - rr) * qq) + (orig >> 3);
  int GM = 1;
  if      (nBM % 8 == 0) GM = 8;
  else if (nBM % 7 == 0) GM = 7;
  else if (nBM % 5 == 0) GM = 5;
  else if (nBM % 4 == 0) GM = 4;
  else if (nBM % 3 == 0) GM = 3;
  else if (nBM % 2 == 0) GM = 2;
  int per = GM * nBN;
  int bm = (wg / per) * GM + (wg % per) % GM;
  int bn = (wg % per) / GM;

  const int wm = w >> 2, wn = w & 3;  // 2 (M) x 4 (N) waves

  // staging source mapping (inverse st_16x32 swizzle; LDS dest linear)
  int rowp0, colp0, rowp1, colp1;
  {
    int p0 = (w * 2 + 0) * 1024 + l * 16;
    int q0 = p0 ^ (((p0 >> 9) & 1) << 5);
    rowp0 = q0 >> 7; colp0 = (q0 & 127) >> 1;
    int p1 = (w * 2 + 1) * 1024 + l * 16;
    int q1 = p1 ^ (((p1 >> 9) & 1) << 5);
    rowp1 = q1 >> 7; colp1 = (q1 & 127) >> 1;
  }
  const int lda = K;
  unsigned aoff0 = (unsigned)((bm * 256 + rowp0) * lda + colp0);
  unsigned aoff1 = (unsigned)((bm * 256 + rowp1) * lda + colp1);
  unsigned boff0 = (unsigned)((bn * 256 + rowp0) * lda + colp0);
  unsigned boff1 = (unsigned)((bn * 256 + rowp1) * lda + colp1);
  const unsigned halfA = 128u * (unsigned)lda;
  const int sdo0 = (w * 2 + 0) * 1024;
  const int sdo1 = (w * 2 + 1) * 1024;

  // ds_read swizzled base addresses
  int aaddr[8];
  #pragma unroll
  for (int f = 0; f < 8; ++f) {
    int row = wm * 128 + f * 16 + lr;
    int sb = row * 128 + lk * 16;
    aaddr[f] = sb ^ (((row >> 2) & 1) << 5);
  }
  int baddr[4];
  #pragma unroll
  for (int f = 0; f < 4; ++f) {
    int row = wn * 64 + f * 16 + lr;
    int sb = row * 128 + lk * 16;
    baddr[f] = 65536 + (sb ^ (((row >> 2) & 1) << 5));
  }

  f32x4 acc[8][4];
  #pragma unroll
  for (int i = 0; i < 8; ++i)
    #pragma unroll
    for (int j = 0; j < 4; ++j) acc[i][j] = (f32x4){0.f, 0.f, 0.f, 0.f};
  f16x8 a[4][2];
  f16x8 b[2][2][2];

  // prologue: B0(0),B1(0),A0(0),A1(0),B0(1),B1(1)
  STG_B(0, 0); STG_B(0, 1); STG_A(0, 0); STG_A(0, 1); STG_B(1, 0); STG_B(1, 1);
  asm volatile("s_waitcnt vmcnt(4)" ::: "memory");
  __builtin_amdgcn_s_barrier();

  const int niter = nt >> 1;
  for (int it = 0; it < niter; ++it) {
    const int u = it * 2, v = u + 1;
    // ph1: tile u (buf0) A(rh0)+B(ch0); stage A0(v)
    DSREAD_A(0, 0); DSREAD_B(0, 0); STG_A(v, 0);
    PHTAIL(0, 0, 0);
    // ph2: B(ch1) u; stage A1(v)
    DSREAD_B(0, 1); STG_A(v, 1);
    PHTAIL(0, 1, 0);
    // ph3: A(rh1) u; stage B0(u+2)
    DSREAD_A(0, 1); STG_B(u + 2, 0);
    PHTAIL(1, 0, 0);
    // ph4: stage B1(u+2); vmcnt
    STG_B(u + 2, 1);
    PHTAIL(1, 1, 1);
    // ph5: tile v (buf1) A(rh0)+B(ch0); stage A0(u+2)
    DSREAD_A(1, 0); DSREAD_B(1, 0); STG_A(u + 2, 0);
    PHTAIL(0, 0, 0);
    // ph6: B(ch1) v; stage A1(u+2)
    DSREAD_B(1, 1); STG_A(u + 2, 1);
    PHTAIL(0, 1, 0);
    // ph7: A(rh1) v; stage B0(v+2)
    DSREAD_A(1, 1); STG_B(v + 2, 0);
    PHTAIL(1, 0, 0);
    // ph8: stage B1(v+2); vmcnt
    STG_B(v + 2, 1);
    PHTAIL(1, 1, 1);
  }

  // epilogue: bias + relu + f16 store
  int crow = bm * 256 + wm * 128;
  int ccol = bn * 256 + wn * 64;
  #pragma unroll
  for (int j = 0; j < 4; ++j) {
    int col = ccol + j * 16 + lr;
    float bj = bias[col];
    #pragma unroll
    for (int i = 0; i < 8; ++i) {
      int rowb = crow + i * 16 + lk * 4;
      #pragma unroll
      for (int r = 0; r < 4; ++r) {
        float vv = acc[i][j][r] + bj;
        vv = fmaxf(vv, 0.f);
        C[(size_t)(rowb + r) * N + col] = (f16)vv;
      }
    }
  }
}

// ---------------------------------------------------------------- pair sum (row-segmented, atomic)
__global__ void pair_sum_seg(const f16* __restrict__ h4, float* __restrict__ hsumT,
                             int rowStart, int nRows, int gb0) {
  int b = gb0 + blockIdx.x;
  if (b >= BATCH) return;
  int r0 = b * 625 - rowStart;       if (r0 < 0) r0 = 0;
  int r1 = (b + 1) * 625 - rowStart; if (r1 > nRows) r1 = nRows;
  int n = r1 - r0;
  if (n <= 0) return;
  int seg = blockIdx.y;
  int s0 = r0 + (n * seg) / 8;
  int s1 = r0 + (n * (seg + 1)) / 8;
  if (s0 >= s1) return;
  int cg = threadIdx.x;
  float acc[8];
  #pragma unroll
  for (int e = 0; e < 8; ++e) acc[e] = 0.f;
  for (int r = s0; r < s1; ++r) {
    f16x8 v = *(const f16x8*)&h4[(size_t)r * 2048 + cg * 8];
    #pragma unroll
    for (int e = 0; e < 8; ++e) acc[e] += (float)v[e];
  }
  #pragma unroll
  for (int e = 0; e < 8; ++e)
    atomicAdd(&hsumT[(size_t)(cg * 8 + e) * BATCH + b], acc[e]);
}

// ---------------------------------------------------------------- fp32 FC (transposed act)
__global__ void fc_t(const float* __restrict__ inT, const float* __restrict__ w,
                     const float* __restrict__ bias, float* __restrict__ outT,
                     int K, int N) {
  int n = blockIdx.x;
  int m = threadIdx.x;
  const float* wr = w + (size_t)n * K;
  float acc = bias[n];
  int k = 0;
  for (; k + 4 <= K; k += 4) {
    acc += inT[(size_t)(k + 0) * BATCH + m] * wr[k + 0]
         + inT[(size_t)(k + 1) * BATCH + m] * wr[k + 1]
         + inT[(size_t)(k + 2) * BATCH + m] * wr[k + 2]
         + inT[(size_t)(k + 3) * BATCH + m] * wr[k + 3];
  }
  for (; k < K; ++k) acc += inT[(size_t)k * BATCH + m] * wr[k];
  outT[(size_t)n * BATCH + m] = fmaxf(acc, 0.f);
}

// ---------------------------------------------------------------- final linear + log_softmax
__global__ void out_lsm(const float* __restrict__ f4T, const float* __restrict__ ow,
                        const float* __restrict__ ob, float* __restrict__ out) {
  int m = threadIdx.x;
  float z[10];
  #pragma unroll
  for (int c = 0; c < 10; ++c) {
    float acc = ob[c];
    for (int k = 0; k < 100; ++k) acc += f4T[(size_t)k * BATCH + m] * ow[c * 100 + k];
    z[c] = fmaxf(acc, 0.f);
  }
  float mx = z[0];
  #pragma unroll
  for (int c = 1; c < 10; ++c) mx = fmaxf(mx, z[c]);
  float s = 0.f;
  #pragma unroll
  for (int c = 0; c < 10; ++c) s += expf(z[c] - mx);
  float lse = mx + logf(s);
  #pragma unroll
  for (int c = 0; c < 10; ++c) out[m * 10 + c] = z[c] - lse;
}

// ---------------------------------------------------------------- host
extern "C" void kernel_launch(void* const* d_in, const int* in_sizes, int n_in,
                              void* d_out, int out_size, void* d_ws, size_t ws_size,
                              hipStream_t stream) {
  const float* image = (const float*)d_in[0];
  const float* questions = (const float*)d_in[1];
  const float* c1w = (const float*)d_in[2];  const float* c1b = (const float*)d_in[3];
  const float* bn1g = (const float*)d_in[4]; const float* bn1b = (const float*)d_in[5];
  const float* c2w = (const float*)d_in[6];  const float* c2b = (const float*)d_in[7];
  const float* bn2g = (const float*)d_in[8]; const float* bn2b = (const float*)d_in[9];
  const float* c3w = (const float*)d_in[10]; const float* c3b = (const float*)d_in[11];
  const float* bn3g = (const float*)d_in[12];const float* bn3b = (const float*)d_in[13];
  const float* c4w = (const float*)d_in[14]; const float* c4b = (const float*)d_in[15];
  const float* bn4g = (const float*)d_in[16];const float* bn4b = (const float*)d_in[17];
  const float* g1w = (const float*)d_in[18]; const float* g1b = (const float*)d_in[19];
  const float* g2w = (const float*)d_in[20]; const float* g2b = (const float*)d_in[21];
  const float* g3w = (const float*)d_in[22]; const float* g3b = (const float*)d_in[23];
  const float* g4w = (const float*)d_in[24]; const float* g4b = (const float*)d_in[25];
  const float* f1w = (const float*)d_in[26]; const float* f1b = (const float*)d_in[27];
  const float* f2w = (const float*)d_in[28]; const float* f2b = (const float*)d_in[29];
  const float* f3w = (const float*)d_in[30]; const float* f3b = (const float*)d_in[31];
  const float* f4w = (const float*)d_in[32]; const float* f4b = (const float*)d_in[33];
  const float* ow  = (const float*)d_in[34]; const float* ob  = (const float*)d_in[35];
  float* out = (float*)d_out;
  (void)in_sizes; (void)n_in; (void)out_size;

  // ---------------- workspace sizing ----
  const size_t MB = 1024ull * 1024;
  const size_t PERSIST =
      2048ull * 640 * 2 + 3ull * 2048 * 2048 * 2 +
      4ull * 2048 * 4 +
      (128ull * 32 + 128 * 288 + 128 * 576 + 256 * 1152) * 2 +
      (128ull + 128 + 128 + 256) * 4 +
      2ull * 205 * 256 * 4 +
      2ull * 256 * 4 +
      3200ull * 256 * 2 +
      2048ull * BATCH * 4 +
      (2000ull + 1000 + 500 + 100) * BATCH * 4 +
      64ull * 256;

  auto need = [&](int CH) -> size_t {
    size_t gsz = (size_t)CH * 4096;                       // CH x 2048 f16
    size_t SA = gsz > 56 * MB ? gsz : 56 * MB;            // floor: y1 52.4MB
    size_t SB = gsz > 30 * MB ? gsz : 30 * MB;            // floor: A2 29.5MB
    size_t rsz = (size_t)CH * 1280;                       // CH x 640 f16
    size_t SC = rsz > 14 * MB ? rsz : 14 * MB;            // floor: y2 13.1MB
    return PERSIST + SA + SB + SC;
  };
  int CH = 2048;
  const int cands[3] = {16128, 8192, 4096};
  for (int ci = 0; ci < 3; ++ci)
    if (need(cands[ci]) <= ws_size) { CH = cands[ci]; break; }

  char* ws = (char*)d_ws;
  size_t off = 0;
  auto alloc = [&](size_t bytes) -> void* {
    void* p = ws + off;
    off += (bytes + 255) & ~(size_t)255;
    return p;
  };
  f16* wg1 = (f16*)alloc(2048ull * 640 * 2);
  f16* wg2 = (f16*)alloc(2048ull * 2048 * 2);
  f16* wg3 = (f16*)alloc(2048ull * 2048 * 2);
  f16* wg4 = (f16*)alloc(2048ull * 2048 * 2);
  float* bgp = (float*)alloc(4 * 2048 * 4);
  f16* wp1 = (f16*)alloc(128ull * 32 * 2);
  f16* wp2 = (f16*)alloc(128ull * 288 * 2);
  f16* wp3 = (f16*)alloc(128ull * 576 * 2);
  f16* wp4 = (f16*)alloc(256ull * 1152 * 2);
  float* bc1p = (float*)alloc(128 * 4);
  float* bc2p = (float*)alloc(128 * 4);
  float* bc3p = (float*)alloc(128 * 4);
  float* bc4p = (float*)alloc(256 * 4);
  float* psum = (float*)alloc(205ull * 256 * 4);
  float* psq  = (float*)alloc(205ull * 256 * 4);
  float* scl  = (float*)alloc(256 * 4);
  float* shf  = (float*)alloc(256 * 4);
  f16* y4 = (f16*)alloc(3200ull * 256 * 2);
  float* hsumT = (float*)alloc(2048ull * BATCH * 4);
  float* f1T = (float*)alloc(2000ull * BATCH * 4);
  float* f2T = (float*)alloc(1000ull * BATCH * 4);
  float* f3T = (float*)alloc(500ull * BATCH * 4);
  float* f4T = (float*)alloc(100ull * BATCH * 4);

  size_t gsz = (size_t)CH * 4096;
  size_t SA = gsz > 56 * MB ? gsz : 56 * MB;
  size_t SB = gsz > 30 * MB ? gsz : 30 * MB;
  size_t rsz = (size_t)CH * 1280;
  size_t SC = rsz > 14 * MB ? rsz : 14 * MB;
  char* regA = (char*)alloc(SA);
  char* regB = (char*)alloc(SB);
  char* regC = (char*)alloc(SC);

  f16* y1 = (f16*)regA;
  f16* A1 = (f16*)regB;
  f16* A2 = (f16*)regB;
  f16* y2 = (f16*)regC;
  f16* A3 = (f16*)regA;
  f16* y3 = (f16*)regB;
  f16* A4 = (f16*)(regB + 4 * MB);
  f16* hA = (f16*)regA;
  f16* hB = (f16*)regB;
  f16* relc = (f16*)regC;

  // ---- weight prep ----
  {
    long t1 = 2048L * 640;
    pad_w_f16<<<(int)((t1 + 255) / 256), 256, 0, stream>>>(g1w, wg1, 2000, 527, 640, t1);
    long t2 = 2048L * 2048;
    pad_w_f16<<<(int)((t2 + 255) / 256), 256, 0, stream>>>(g2w, wg2, 2000, 2000, 2048, t2);
    pad_w_f16<<<(int)((t2 + 255) / 256), 256, 0, stream>>>(g3w, wg3, 2000, 2000, 2048, t2);
    pad_w_f16<<<(int)((t2 + 255) / 256), 256, 0, stream>>>(g4w, wg4, 2000, 2000, 2048, t2);
    pad_bias<<<8, 256, 0, stream>>>(g1b, bgp + 0 * 2048, 2000, 2048);
    pad_bias<<<8, 256, 0, stream>>>(g2b, bgp + 1 * 2048, 2000, 2048);
    pad_bias<<<8, 256, 0, stream>>>(g3b, bgp + 2 * 2048, 2000, 2048);
    pad_bias<<<8, 256, 0, stream>>>(g4b, bgp + 3 * 2048, 2000, 2048);
    prep_convw<<<(128 * 32 + 255) / 256, 256, 0, stream>>>(c1w, wp1, 32, 3, 128, 32);
    prep_convw<<<(128 * 288 + 255) / 256, 256, 0, stream>>>(c2w, wp2, 64, 32, 128, 288);
    prep_convw<<<(128 * 576 + 255) / 256, 256, 0, stream>>>(c3w, wp3, 128, 64, 128, 576);
    prep_convw<<<(256 * 1152 + 255) / 256, 256, 0, stream>>>(c4w, wp4, 256, 128, 256, 1152);
    pad_bias<<<1, 256, 0, stream>>>(c1b, bc1p, 32, 128);
    pad_bias<<<1, 256, 0, stream>>>(c2b, bc2p, 64, 128);
    pad_bias<<<1, 256, 0, stream>>>(c3b, bc3p, 128, 128);
    pad_bias<<<1, 256, 0, stream>>>(c4b, bc4p, 256, 256);
  }

  // ---- conv stack: im2col + gemm(128^2) + BN ----
  im2col1<<<(204800 * 32 + 255) / 256, 256, 0, stream>>>(image, A1);
  gemm_f16<<<1600, 256, 0, stream>>>(A1, wp1, bc1p, y1, 204800, 128, 32);
  bn_part<<<200, 256, 0, stream>>>(y1, psum, psq, 204800, 128, 1024);
  bn_final<<<1, 256, 0, stream>>>(psum, psq, bn1g, bn1b, scl, shf, 200, 128, 32, 204800);
  bn_apply<<<(int)((204800L * 16 + 255) / 256), 256, 0, stream>>>(y1, scl, shf, 204800L * 16, 128);
  { long t = 51200L * 9 * 4;
    im2col_nhwc<<<(int)((t + 255) / 256), 256, 0, stream>>>(y1, A2, 40, 40, 20, 20, 128, 32, 288, t); }
  gemm_f16<<<400, 256, 0, stream>>>(A2, wp2, bc2p, y2, 51200, 128, 288);
  bn_part<<<50, 256, 0, stream>>>(y2, psum, psq, 51200, 128, 1024);
  bn_final<<<1, 256, 0, stream>>>(psum, psq, bn2g, bn2b, scl, shf, 50, 128, 64, 51200);
  bn_apply<<<(int)((51200L * 16 + 255) / 256), 256, 0, stream>>>(y2, scl, shf, 51200L * 16, 128);
  { long t = 12800L * 9 * 8;
    im2col_nhwc<<<(int)((t + 255) / 256), 256, 0, stream>>>(y2, A3, 20, 20, 10, 10, 128, 64, 576, t); }
  gemm_f16<<<100, 256, 0, stream>>>(A3, wp3, bc3p, y3, 12800, 128, 576);
  bn_part<<<13, 256, 0, stream>>>(y3, psum, psq, 12800, 128, 1024);
  bn_final<<<1, 256, 0, stream>>>(psum, psq, bn3g, bn3b, scl, shf, 13, 128, 128, 12800);
  bn_apply<<<(int)((12800L * 16 + 255) / 256), 256, 0, stream>>>(y3, scl, shf, 12800L * 16, 128);
  { long t = 3200L * 9 * 16;
    im2col_nhwc<<<(int)((t + 255) / 256), 256, 0, stream>>>(y3, A4, 10, 10, 5, 5, 128, 128, 1152, t); }
  gemm_f16<<<50, 256, 0, stream>>>(A4, wp4, bc4p, y4, 3200, 256, 1152);
  bn_part<<<4, 256, 0, stream>>>(y4, psum, psq, 3200, 256, 1024);
  bn_final<<<1, 256, 0, stream>>>(psum, psq, bn4g, bn4b, scl, shf, 4, 256, 256, 3200);
  bn_apply<<<(int)((3200L * 32 + 255) / 256), 256, 0, stream>>>(y4, scl, shf, 3200L * 32, 256);

  // ---- g-MLP (chunked, 256^2 8-phase GEMM) + pair sum ----
  hipMemsetAsync(hsumT, 0, 2048ull * BATCH * 4, stream);
  for (int start = 0; start < 80000; start += CH) {
    int M = 80000 - start;
    if (M > CH) M = CH;
    int Mp = (M + 255) & ~255;
    long tr = (long)Mp * 80;
    build_rel8<<<(int)((tr + 255) / 256), 256, 0, stream>>>(y4, questions, relc, start, Mp);
    int ng = (Mp / 256) * 8;
    gemm256<<<ng, 512, 0, stream>>>(relc, wg1, bgp + 0 * 2048, hA, Mp, 2048, 640);
    gemm256<<<ng, 512, 0, stream>>>(hA, wg2, bgp + 1 * 2048, hB, Mp, 2048, 2048);
    gemm256<<<ng, 512, 0, stream>>>(hB, wg3, bgp + 2 * 2048, hA, Mp, 2048, 2048);
    gemm256<<<ng, 512, 0, stream>>>(hA, wg4, bgp + 3 * 2048, hB, Mp, 2048, 2048);
    int gb0 = start / 625;
    int gb1 = (start + M - 1) / 625;
    dim3 sgrid(gb1 - gb0 + 1, 8);
    pair_sum_seg<<<sgrid, 256, 0, stream>>>(hB, hsumT, start, M, gb0);
  }

  // ---- f-MLP ----
  fc_t<<<2000, 128, 0, stream>>>(hsumT, f1w, f1b, f1T, 2000, 2000);
  fc_t<<<1000, 128, 0, stream>>>(f1T, f2w, f2b, f2T, 2000, 1000);
  fc_t<<<500, 128, 0, stream>>>(f2T, f3w, f3b, f3T, 1000, 500);
  fc_t<<<100, 128, 0, stream>>>(f3T, f4w, f4b, f4T, 500, 100);
  out_lsm<<<1, 128, 0, stream>>>(f4T, ow, ob, out);
}

// Round 8
// 3361.740 us; speedup vs baseline: 2.3801x; 1.0501x over previous
//
#include <hip/hip_runtime.h>
#include <hip/hip_fp16.h>
#include <cstdint>

typedef _Float16 f16;
typedef _Float16 f16x8 __attribute__((ext_vector_type(8)));
typedef float f32x4 __attribute__((ext_vector_type(4)));

#define BATCH 128

// ---------------------------------------------------------------- weight prep
__global__ void pad_w_f16(const float* __restrict__ w, f16* __restrict__ o,
                          int N, int K, int Kp, long total) {
  long idx = (long)blockIdx.x * blockDim.x + threadIdx.x;
  if (idx >= total) return;
  int k = (int)(idx % Kp);
  int n = (int)(idx / Kp);
  float v = (n < N && k < K) ? w[(size_t)n * K + k] : 0.f;
  o[idx] = (f16)v;
}

__global__ void pad_bias(const float* __restrict__ b, float* __restrict__ o, int N, int Np) {
  int i = blockIdx.x * blockDim.x + threadIdx.x;
  if (i < Np) o[i] = (i < N) ? b[i] : 0.f;
}

__global__ void prep_convw(const float* __restrict__ w, f16* __restrict__ o,
                           int CO, int CI, int COp, int Kp) {
  int idx = blockIdx.x * blockDim.x + threadIdx.x;
  int total = COp * Kp;
  if (idx >= total) return;
  int k = idx % Kp;
  int co = idx / Kp;
  float v = 0.f;
  if (co < CO && k < 9 * CI) {
    int tap = k / CI, ci = k % CI;
    v = w[((size_t)co * CI + ci) * 9 + tap];
  }
  o[idx] = (f16)v;
}

// ---------------------------------------------------------------- im2col
__global__ void im2col1(const float* __restrict__ img, f16* __restrict__ A) {
  int idx = blockIdx.x * blockDim.x + threadIdx.x;
  const int total = 204800 * 32;
  if (idx >= total) return;
  int k = idx & 31;
  int m = idx >> 5;
  int ox = m % 40; int t = m / 40;
  int oy = t % 40; int b = t / 40;
  float v = 0.f;
  if (k < 27) {
    int tap = k / 3, ci = k % 3;
    int iy = oy * 2 - 1 + tap / 3;
    int ix = ox * 2 - 1 + tap % 3;
    if ((unsigned)iy < 80u && (unsigned)ix < 80u)
      v = img[(((size_t)b * 3 + ci) * 80 + iy) * 80 + ix];
  }
  A[idx] = (f16)v;
}

__global__ void im2col_nhwc(const f16* __restrict__ y, f16* __restrict__ A,
                            int H, int W, int OH, int OW, int Cs, int Cv, int Kp,
                            long total) {
  long idx = (long)blockIdx.x * blockDim.x + threadIdx.x;
  if (idx >= total) return;
  int G = Cv >> 3;
  int cg = (int)(idx % G);
  long t = idx / G;
  int tap = (int)(t % 9);
  int m = (int)(t / 9);
  int ox = m % OW; int t2 = m / OW;
  int oy = t2 % OH; int b = t2 / OH;
  int iy = oy * 2 - 1 + tap / 3;
  int ix = ox * 2 - 1 + tap % 3;
  f16x8 v = {};
  if ((unsigned)iy < (unsigned)H && (unsigned)ix < (unsigned)W)
    v = *(const f16x8*)&y[(((size_t)b * H + iy) * W + ix) * Cs + cg * 8];
  *(f16x8*)&A[(size_t)m * Kp + tap * Cv + cg * 8] = v;
}

// ---------------------------------------------------------------- batchnorm (NHWC, two-stage)
__global__ void bn_part(const f16* __restrict__ y, float* __restrict__ psum,
                        float* __restrict__ psq, int M, int Cs, int RPB) {
  int G = Cs >> 3;
  int R = 256 / G;
  int tid = threadIdx.x;
  int g = tid % G, r = tid / G;
  int row0 = blockIdx.x * RPB;
  int rowEnd = row0 + RPB; if (rowEnd > M) rowEnd = M;
  float s[8], q[8];
  #pragma unroll
  for (int e = 0; e < 8; ++e) { s[e] = 0.f; q[e] = 0.f; }
  for (int row = row0 + r; row < rowEnd; row += R) {
    f16x8 v = *(const f16x8*)&y[(size_t)row * Cs + g * 8];
    #pragma unroll
    for (int e = 0; e < 8; ++e) { float f = (float)v[e]; s[e] += f; q[e] += f * f; }
  }
  __shared__ float ls[256 * 8];
  __shared__ float lq[256 * 8];
  #pragma unroll
  for (int e = 0; e < 8; ++e) { ls[tid * 8 + e] = s[e]; lq[tid * 8 + e] = q[e]; }
  __syncthreads();
  for (int st = R / 2; st > 0; st >>= 1) {
    if (r < st) {
      int o = tid * 8, p = (tid + st * G) * 8;
      #pragma unroll
      for (int e = 0; e < 8; ++e) { ls[o + e] += ls[p + e]; lq[o + e] += lq[p + e]; }
    }
    __syncthreads();
  }
  if (r == 0) {
    #pragma unroll
    for (int e = 0; e < 8; ++e) {
      psum[(size_t)blockIdx.x * Cs + g * 8 + e] = ls[tid * 8 + e];
      psq [(size_t)blockIdx.x * Cs + g * 8 + e] = lq[tid * 8 + e];
    }
  }
}

__global__ void bn_final(const float* __restrict__ psum, const float* __restrict__ psq,
                         const float* __restrict__ g, const float* __restrict__ beta,
                         float* __restrict__ scale, float* __restrict__ shift,
                         int nblk, int Cs, int Cv, int M) {
  int c = threadIdx.x;
  if (c >= Cs) return;
  float s = 0.f, q = 0.f;
  for (int b = 0; b < nblk; ++b) { s += psum[(size_t)b * Cs + c]; q += psq[(size_t)b * Cs + c]; }
  float inv = 1.f / (float)M;
  float m = s * inv;
  float var = q * inv - m * m;
  if (c < Cv) {
    float sc = g[c] * rsqrtf(var + 1e-5f);
    scale[c] = sc;
    shift[c] = beta[c] - m * sc;
  } else {
    scale[c] = 0.f;
    shift[c] = 0.f;
  }
}

__global__ void bn_apply(f16* __restrict__ y, const float* __restrict__ scale,
                         const float* __restrict__ shift, long totalGroups, int Cs) {
  long idx = (long)blockIdx.x * blockDim.x + threadIdx.x;
  if (idx >= totalGroups) return;
  int G = Cs >> 3;
  int cg = (int)(idx % G);
  long m = idx / G;
  f16x8 v = *(const f16x8*)&y[m * Cs + cg * 8];
  #pragma unroll
  for (int e = 0; e < 8; ++e)
    v[e] = (f16)((float)v[e] * scale[cg * 8 + e] + shift[cg * 8 + e]);
  *(f16x8*)&y[m * Cs + cg * 8] = v;
}

// ---------------------------------------------------------------- rel build (stride 640, zero-padded)
__global__ void build_rel8(const f16* __restrict__ y4, const float* __restrict__ q,
                           f16* __restrict__ rel, int rowStart, int nRowsPad) {
  long idx = (long)blockIdx.x * blockDim.x + threadIdx.x;
  long total = (long)nRowsPad * 80;
  if (idx >= total) return;
  int kg = (int)(idx % 80);
  long t = idx / 80;
  long grow = rowStart + t;
  int k0 = kg * 8;
  f16x8 v = {};
  if (grow < 80000) {
    int pair = (int)(grow % 625);
    int b = (int)(grow / 625);
    int i = pair / 25, j = pair % 25;
    const f16* yj = y4 + ((size_t)b * 25 + j) * 256;
    const f16* yi = y4 + ((size_t)b * 25 + i) * 256;
    if (k0 < 256) {
      v = *(const f16x8*)&yj[k0];
    } else if (k0 >= 264 && k0 + 8 <= 514) {
      #pragma unroll
      for (int e = 0; e < 8; ++e) v[e] = yi[k0 + e - 258];
    } else if (k0 < 528) {
      #pragma unroll
      for (int e = 0; e < 8; ++e) {
        int k = k0 + e;
        float f;
        if (k < 256)       f = (float)yj[k];
        else if (k == 256) f = (float)(j / 5) * 0.5f - 1.f;
        else if (k == 257) f = (float)(j % 5) * 0.5f - 1.f;
        else if (k < 514)  f = (float)yi[k - 258];
        else if (k == 514) f = (float)(i / 5) * 0.5f - 1.f;
        else if (k == 515) f = (float)(i % 5) * 0.5f - 1.f;
        else if (k < 527)  f = q[b * 11 + (k - 516)];
        else               f = 0.f;
        v[e] = (f16)f;
      }
    }
  }
  *(f16x8*)&rel[t * 640 + k0] = v;
}

// ---------------------------------------------------------------- async global->LDS helper
__device__ __forceinline__ void load_lds16(const void* g, void* l) {
  __builtin_amdgcn_global_load_lds((const __attribute__((address_space(1))) unsigned int*)g,
                                   (__attribute__((address_space(3))) unsigned int*)l,
                                   16, 0, 0);
}

// ---------------------------------------------------------------- fp16 MFMA GEMM 128^2 (m97 structure) — conv layers
__global__ __launch_bounds__(256) void gemm_f16(const f16* __restrict__ A,
                                                const f16* __restrict__ Bw,
                                                const float* __restrict__ bias,
                                                f16* __restrict__ C,
                                                int M, int N, int K) {
  __shared__ __align__(16) f16 As[128 * 32];
  __shared__ __align__(16) f16 Bs[128 * 32];
  int tid = threadIdx.x;
  int wv = tid >> 6, l = tid & 63;

  int nBM = M >> 7, nBN = N >> 7;
  int nwg = nBM * nBN;
  int orig = blockIdx.x;
  int qq = nwg >> 3, rr = nwg & 7;
  int xcd = orig & 7;
  int wg = (xcd < rr ? xcd * (qq + 1) : rr * (qq + 1) + (xcd - rr) * qq) + (orig >> 3);
  int GM = (nBM % 5 == 0) ? 5 : (nBM % 4 == 0) ? 4 : (nBM % 2 == 0) ? 2 : 1;
  int per = GM * nBN;
  int grp = wg / per;
  int inn = wg % per;
  int bm = grp * GM + (inn % GM);
  int bn = inn / GM;

  int wm = wv >> 1, wn = wv & 1;
  int lr = l & 15, lk = l >> 4;

  int e0 = (wv * 2) * 64 + l;
  int e1 = e0 + 64;
  int r0 = e0 >> 2, ch0 = e0 & 3;
  int r1 = e1 >> 2, ch1 = e1 & 3;
  const f16* ga0 = A + (size_t)(bm * 128 + r0) * K + ch0 * 8;
  const f16* ga1 = A + (size_t)(bm * 128 + r1) * K + ch1 * 8;
  const f16* gb0 = Bw + (size_t)(bn * 128 + r0) * K + ch0 * 8;
  const f16* gb1 = Bw + (size_t)(bn * 128 + r1) * K + ch1 * 8;
  f16* la0 = As + (wv * 2 + 0) * 512;
  f16* la1 = As + (wv * 2 + 1) * 512;
  f16* lb0 = Bs + (wv * 2 + 0) * 512;
  f16* lb1 = Bs + (wv * 2 + 1) * 512;

  f32x4 zero = {0.f, 0.f, 0.f, 0.f};
  f32x4 acc[4][4];
  #pragma unroll
  for (int i = 0; i < 4; ++i)
    #pragma unroll
    for (int j = 0; j < 4; ++j) acc[i][j] = zero;

  int nk = K >> 5;
  for (int kt = 0; kt < nk; ++kt) {
    __syncthreads();
    load_lds16(ga0, la0);
    load_lds16(ga1, la1);
    load_lds16(gb0, lb0);
    load_lds16(gb1, lb1);
    ga0 += 32; ga1 += 32; gb0 += 32; gb1 += 32;
    __syncthreads();
    f16x8 af[4], bf[4];
    #pragma unroll
    for (int i = 0; i < 4; ++i)
      af[i] = *(const f16x8*)&As[(wm * 64 + i * 16 + lr) * 32 + lk * 8];
    #pragma unroll
    for (int j = 0; j < 4; ++j)
      bf[j] = *(const f16x8*)&Bs[(wn * 64 + j * 16 + lr) * 32 + lk * 8];
    #pragma unroll
    for (int i = 0; i < 4; ++i)
      #pragma unroll
      for (int j = 0; j < 4; ++j)
        acc[i][j] = __builtin_amdgcn_mfma_f32_16x16x32_f16(af[i], bf[j], acc[i][j], 0, 0, 0);
  }

  int crow = bm * 128 + wm * 64;
  int ccol = bn * 128 + wn * 64;
  #pragma unroll
  for (int j = 0; j < 4; ++j) {
    int col = ccol + j * 16 + lr;
    float bj = bias[col];
    #pragma unroll
    for (int i = 0; i < 4; ++i) {
      int rowb = crow + i * 16 + lk * 4;
      #pragma unroll
      for (int r = 0; r < 4; ++r) {
        float v = acc[i][j][r] + bj;
        v = fmaxf(v, 0.f);
        C[(size_t)(rowb + r) * N + col] = (f16)v;
      }
    }
  }
}

// ---------------------------------------------------------------- fp16 MFMA GEMM 256^2, BK=64, 8-phase pipeline
// LDS half-tile rows are 128B; full 3-bit XOR swizzle: 16B-slot t of row r holds
// logical slot t ^ (r&7). Staging source pre-applies the same involution (rule #21).
#define DSREAD_A(BUF, RH) do { \
  a[0][0] = *(const f16x8*)(lds + ((BUF) << 15) + aaddr0[(RH)*4 + 0]); \
  a[0][1] = *(const f16x8*)(lds + ((BUF) << 15) + aaddr1[(RH)*4 + 0]); \
  a[1][0] = *(const f16x8*)(lds + ((BUF) << 15) + aaddr0[(RH)*4 + 1]); \
  a[1][1] = *(const f16x8*)(lds + ((BUF) << 15) + aaddr1[(RH)*4 + 1]); \
  a[2][0] = *(const f16x8*)(lds + ((BUF) << 15) + aaddr0[(RH)*4 + 2]); \
  a[2][1] = *(const f16x8*)(lds + ((BUF) << 15) + aaddr1[(RH)*4 + 2]); \
  a[3][0] = *(const f16x8*)(lds + ((BUF) << 15) + aaddr0[(RH)*4 + 3]); \
  a[3][1] = *(const f16x8*)(lds + ((BUF) << 15) + aaddr1[(RH)*4 + 3]); \
} while (0)

#define DSREAD_B(BUF, CH) do { \
  b[CH][0][0] = *(const f16x8*)(lds + ((BUF) << 15) + baddr0[(CH)*2 + 0]); \
  b[CH][0][1] = *(const f16x8*)(lds + ((BUF) << 15) + baddr1[(CH)*2 + 0]); \
  b[CH][1][0] = *(const f16x8*)(lds + ((BUF) << 15) + baddr0[(CH)*2 + 1]); \
  b[CH][1][1] = *(const f16x8*)(lds + ((BUF) << 15) + baddr1[(CH)*2 + 1]); \
} while (0)

#define MFMA16(RH, CH) do { \
  acc[(RH)*4+0][(CH)*2+0] = __builtin_amdgcn_mfma_f32_16x16x32_f16(a[0][0], b[CH][0][0], acc[(RH)*4+0][(CH)*2+0], 0,0,0); \
  acc[(RH)*4+0][(CH)*2+0] = __builtin_amdgcn_mfma_f32_16x16x32_f16(a[0][1], b[CH][0][1], acc[(RH)*4+0][(CH)*2+0], 0,0,0); \
  acc[(RH)*4+0][(CH)*2+1] = __builtin_amdgcn_mfma_f32_16x16x32_f16(a[0][0], b[CH][1][0], acc[(RH)*4+0][(CH)*2+1], 0,0,0); \
  acc[(RH)*4+0][(CH)*2+1] = __builtin_amdgcn_mfma_f32_16x16x32_f16(a[0][1], b[CH][1][1], acc[(RH)*4+0][(CH)*2+1], 0,0,0); \
  acc[(RH)*4+1][(CH)*2+0] = __builtin_amdgcn_mfma_f32_16x16x32_f16(a[1][0], b[CH][0][0], acc[(RH)*4+1][(CH)*2+0], 0,0,0); \
  acc[(RH)*4+1][(CH)*2+0] = __builtin_amdgcn_mfma_f32_16x16x32_f16(a[1][1], b[CH][0][1], acc[(RH)*4+1][(CH)*2+0], 0,0,0); \
  acc[(RH)*4+1][(CH)*2+1] = __builtin_amdgcn_mfma_f32_16x16x32_f16(a[1][0], b[CH][1][0], acc[(RH)*4+1][(CH)*2+1], 0,0,0); \
  acc[(RH)*4+1][(CH)*2+1] = __builtin_amdgcn_mfma_f32_16x16x32_f16(a[1][1], b[CH][1][1], acc[(RH)*4+1][(CH)*2+1], 0,0,0); \
  acc[(RH)*4+2][(CH)*2+0] = __builtin_amdgcn_mfma_f32_16x16x32_f16(a[2][0], b[CH][0][0], acc[(RH)*4+2][(CH)*2+0], 0,0,0); \
  acc[(RH)*4+2][(CH)*2+0] = __builtin_amdgcn_mfma_f32_16x16x32_f16(a[2][1], b[CH][0][1], acc[(RH)*4+2][(CH)*2+0], 0,0,0); \
  acc[(RH)*4+2][(CH)*2+1] = __builtin_amdgcn_mfma_f32_16x16x32_f16(a[2][0], b[CH][1][0], acc[(RH)*4+2][(CH)*2+1], 0,0,0); \
  acc[(RH)*4+2][(CH)*2+1] = __builtin_amdgcn_mfma_f32_16x16x32_f16(a[2][1], b[CH][1][1], acc[(RH)*4+2][(CH)*2+1], 0,0,0); \
  acc[(RH)*4+3][(CH)*2+0] = __builtin_amdgcn_mfma_f32_16x16x32_f16(a[3][0], b[CH][0][0], acc[(RH)*4+3][(CH)*2+0], 0,0,0); \
  acc[(RH)*4+3][(CH)*2+0] = __builtin_amdgcn_mfma_f32_16x16x32_f16(a[3][1], b[CH][0][1], acc[(RH)*4+3][(CH)*2+0], 0,0,0); \
  acc[(RH)*4+3][(CH)*2+1] = __builtin_amdgcn_mfma_f32_16x16x32_f16(a[3][0], b[CH][1][0], acc[(RH)*4+3][(CH)*2+1], 0,0,0); \
  acc[(RH)*4+3][(CH)*2+1] = __builtin_amdgcn_mfma_f32_16x16x32_f16(a[3][1], b[CH][1][1], acc[(RH)*4+3][(CH)*2+1], 0,0,0); \
} while (0)

#define PHTAIL(RH, CH, VM) do { \
  __builtin_amdgcn_s_barrier(); \
  asm volatile("s_waitcnt lgkmcnt(0)" ::: "memory"); \
  __builtin_amdgcn_sched_barrier(0); \
  __builtin_amdgcn_s_setprio(1); \
  MFMA16(RH, CH); \
  __builtin_amdgcn_s_setprio(0); \
  __builtin_amdgcn_sched_barrier(0); \
  if (VM) { asm volatile("s_waitcnt vmcnt(4)" ::: "memory"); } \
  __builtin_amdgcn_s_barrier(); \
} while (0)

#define STG_A(T, H) do { int t_ = (T); if (t_ < nt) { int lb = ((t_ & 1) << 15) + ((H) << 14); \
  load_lds16(A  + aoff0 + (size_t)(H) * halfA + (size_t)t_ * 64, lds + lb + sdo0); \
  load_lds16(A  + aoff1 + (size_t)(H) * halfA + (size_t)t_ * 64, lds + lb + sdo1); } } while (0)

#define STG_B(T, H) do { int t_ = (T); if (t_ < nt) { int lb = 65536 + ((t_ & 1) << 15) + ((H) << 14); \
  load_lds16(Bw + boff0 + (size_t)(H) * halfA + (size_t)t_ * 64, lds + lb + sdo0); \
  load_lds16(Bw + boff1 + (size_t)(H) * halfA + (size_t)t_ * 64, lds + lb + sdo1); } } while (0)

__global__ __launch_bounds__(512, 1) void gemm256(const f16* __restrict__ A,
                                                  const f16* __restrict__ Bw,
                                                  const float* __restrict__ bias,
                                                  f16* __restrict__ C,
                                                  int M, int N, int K) {
  __shared__ __align__(16) char lds[131072];
  const int tid = threadIdx.x;
  const int w = tid >> 6, l = tid & 63;
  const int lr = l & 15, lk = l >> 4;
  const int nt = K >> 6;

  // tile swizzle (bijective XCD + GM grouping)
  int nBM = M >> 8, nBN = N >> 8;
  int nwg = nBM * nBN;
  int orig = blockIdx.x;
  int qq = nwg >> 3, rr = nwg & 7;
  int xcd = orig & 7;
  int wg = (xcd < rr ? xcd * (qq + 1) : rr * (qq + 1) + (xcd - rr) * qq) + (orig >> 3);
  int GM = 1;
  if      (nBM % 8 == 0) GM = 8;
  else if (nBM % 7 == 0) GM = 7;
  else if (nBM % 5 == 0) GM = 5;
  else if (nBM % 4 == 0) GM = 4;
  else if (nBM % 3 == 0) GM = 3;
  else if (nBM % 2 == 0) GM = 2;
  int per = GM * nBN;
  int bm = (wg / per) * GM + (wg % per) % GM;
  int bn = (wg % per) / GM;

  const int wm = w >> 2, wn = w & 3;  // 2 (M) x 4 (N) waves

  // staging source mapping (inverse of the 3-bit XOR swizzle; LDS dest linear)
  int rowp0, colp0, rowp1, colp1;
  {
    int p0 = (w * 2 + 0) * 1024 + l * 16;
    int row0_ = p0 >> 7;
    int q0 = p0 ^ ((row0_ & 7) << 4);
    rowp0 = row0_; colp0 = (q0 & 127) >> 1;
    int p1 = (w * 2 + 1) * 1024 + l * 16;
    int row1_ = p1 >> 7;
    int q1 = p1 ^ ((row1_ & 7) << 4);
    rowp1 = row1_; colp1 = (q1 & 127) >> 1;
  }
  const int lda = K;
  unsigned aoff0 = (unsigned)((bm * 256 + rowp0) * lda + colp0);
  unsigned aoff1 = (unsigned)((bm * 256 + rowp1) * lda + colp1);
  unsigned boff0 = (unsigned)((bn * 256 + rowp0) * lda + colp0);
  unsigned boff1 = (unsigned)((bn * 256 + rowp1) * lda + colp1);
  const unsigned halfA = 128u * (unsigned)lda;
  const int sdo0 = (w * 2 + 0) * 1024;
  const int sdo1 = (w * 2 + 1) * 1024;

  // ds_read swizzled addresses: slot(lk) -> lk ^ (row&7); k-half 1 at slot lk+4
  int aaddr0[8], aaddr1[8];
  #pragma unroll
  for (int f = 0; f < 8; ++f) {
    int row = wm * 128 + f * 16 + lr;
    int s = row & 7;
    aaddr0[f] = row * 128 + ((lk ^ s) << 4);
    aaddr1[f] = row * 128 + (((lk + 4) ^ s) << 4);
  }
  int baddr0[4], baddr1[4];
  #pragma unroll
  for (int f = 0; f < 4; ++f) {
    int row = wn * 64 + f * 16 + lr;
    int s = row & 7;
    baddr0[f] = 65536 + row * 128 + ((lk ^ s) << 4);
    baddr1[f] = 65536 + row * 128 + (((lk + 4) ^ s) << 4);
  }

  f32x4 acc[8][4];
  #pragma unroll
  for (int i = 0; i < 8; ++i)
    #pragma unroll
    for (int j = 0; j < 4; ++j) acc[i][j] = (f32x4){0.f, 0.f, 0.f, 0.f};
  f16x8 a[4][2];
  f16x8 b[2][2][2];

  // prologue: B0(0),B1(0),A0(0),A1(0),B0(1),B1(1)
  STG_B(0, 0); STG_B(0, 1); STG_A(0, 0); STG_A(0, 1); STG_B(1, 0); STG_B(1, 1);
  asm volatile("s_waitcnt vmcnt(4)" ::: "memory");
  __builtin_amdgcn_s_barrier();

  const int niter = nt >> 1;
  for (int it = 0; it < niter; ++it) {
    const int u = it * 2, v = u + 1;
    DSREAD_A(0, 0); DSREAD_B(0, 0); STG_A(v, 0);
    PHTAIL(0, 0, 0);
    DSREAD_B(0, 1); STG_A(v, 1);
    PHTAIL(0, 1, 0);
    DSREAD_A(0, 1); STG_B(u + 2, 0);
    PHTAIL(1, 0, 0);
    STG_B(u + 2, 1);
    PHTAIL(1, 1, 1);
    DSREAD_A(1, 0); DSREAD_B(1, 0); STG_A(u + 2, 0);
    PHTAIL(0, 0, 0);
    DSREAD_B(1, 1); STG_A(u + 2, 1);
    PHTAIL(0, 1, 0);
    DSREAD_A(1, 1); STG_B(v + 2, 0);
    PHTAIL(1, 0, 0);
    STG_B(v + 2, 1);
    PHTAIL(1, 1, 1);
  }

  // epilogue: bias + relu + f16 store
  int crow = bm * 256 + wm * 128;
  int ccol = bn * 256 + wn * 64;
  #pragma unroll
  for (int j = 0; j < 4; ++j) {
    int col = ccol + j * 16 + lr;
    float bj = bias[col];
    #pragma unroll
    for (int i = 0; i < 8; ++i) {
      int rowb = crow + i * 16 + lk * 4;
      #pragma unroll
      for (int r = 0; r < 4; ++r) {
        float vv = acc[i][j][r] + bj;
        vv = fmaxf(vv, 0.f);
        C[(size_t)(rowb + r) * N + col] = (f16)vv;
      }
    }
  }
}

// ---------------------------------------------------------------- pair sum (row-segmented, atomic)
__global__ void pair_sum_seg(const f16* __restrict__ h4, float* __restrict__ hsumT,
                             int rowStart, int nRows, int gb0) {
  int b = gb0 + blockIdx.x;
  if (b >= BATCH) return;
  int r0 = b * 625 - rowStart;       if (r0 < 0) r0 = 0;
  int r1 = (b + 1) * 625 - rowStart; if (r1 > nRows) r1 = nRows;
  int n = r1 - r0;
  if (n <= 0) return;
  int seg = blockIdx.y;
  int s0 = r0 + (n * seg) / 8;
  int s1 = r0 + (n * (seg + 1)) / 8;
  if (s0 >= s1) return;
  int cg = threadIdx.x;
  float acc[8];
  #pragma unroll
  for (int e = 0; e < 8; ++e) acc[e] = 0.f;
  for (int r = s0; r < s1; ++r) {
    f16x8 v = *(const f16x8*)&h4[(size_t)r * 2048 + cg * 8];
    #pragma unroll
    for (int e = 0; e < 8; ++e) acc[e] += (float)v[e];
  }
  #pragma unroll
  for (int e = 0; e < 8; ++e)
    atomicAdd(&hsumT[(size_t)(cg * 8 + e) * BATCH + b], acc[e]);
}

// ---------------------------------------------------------------- fp32 FC (transposed act)
__global__ void fc_t(const float* __restrict__ inT, const float* __restrict__ w,
                     const float* __restrict__ bias, float* __restrict__ outT,
                     int K, int N) {
  int n = blockIdx.x;
  int m = threadIdx.x;
  const float* wr = w + (size_t)n * K;
  float acc = bias[n];
  int k = 0;
  for (; k + 4 <= K; k += 4) {
    acc += inT[(size_t)(k + 0) * BATCH + m] * wr[k + 0]
         + inT[(size_t)(k + 1) * BATCH + m] * wr[k + 1]
         + inT[(size_t)(k + 2) * BATCH + m] * wr[k + 2]
         + inT[(size_t)(k + 3) * BATCH + m] * wr[k + 3];
  }
  for (; k < K; ++k) acc += inT[(size_t)k * BATCH + m] * wr[k];
  outT[(size_t)n * BATCH + m] = fmaxf(acc, 0.f);
}

// ---------------------------------------------------------------- final linear + log_softmax
__global__ void out_lsm(const float* __restrict__ f4T, const float* __restrict__ ow,
                        const float* __restrict__ ob, float* __restrict__ out) {
  int m = threadIdx.x;
  float z[10];
  #pragma unroll
  for (int c = 0; c < 10; ++c) {
    float acc = ob[c];
    for (int k = 0; k < 100; ++k) acc += f4T[(size_t)k * BATCH + m] * ow[c * 100 + k];
    z[c] = fmaxf(acc, 0.f);
  }
  float mx = z[0];
  #pragma unroll
  for (int c = 1; c < 10; ++c) mx = fmaxf(mx, z[c]);
  float s = 0.f;
  #pragma unroll
  for (int c = 0; c < 10; ++c) s += expf(z[c] - mx);
  float lse = mx + logf(s);
  #pragma unroll
  for (int c = 0; c < 10; ++c) out[m * 10 + c] = z[c] - lse;
}

// ---------------------------------------------------------------- host
extern "C" void kernel_launch(void* const* d_in, const int* in_sizes, int n_in,
                              void* d_out, int out_size, void* d_ws, size_t ws_size,
                              hipStream_t stream) {
  const float* image = (const float*)d_in[0];
  const float* questions = (const float*)d_in[1];
  const float* c1w = (const float*)d_in[2];  const float* c1b = (const float*)d_in[3];
  const float* bn1g = (const float*)d_in[4]; const float* bn1b = (const float*)d_in[5];
  const float* c2w = (const float*)d_in[6];  const float* c2b = (const float*)d_in[7];
  const float* bn2g = (const float*)d_in[8]; const float* bn2b = (const float*)d_in[9];
  const float* c3w = (const float*)d_in[10]; const float* c3b = (const float*)d_in[11];
  const float* bn3g = (const float*)d_in[12];const float* bn3b = (const float*)d_in[13];
  const float* c4w = (const float*)d_in[14]; const float* c4b = (const float*)d_in[15];
  const float* bn4g = (const float*)d_in[16];const float* bn4b = (const float*)d_in[17];
  const float* g1w = (const float*)d_in[18]; const float* g1b = (const float*)d_in[19];
  const float* g2w = (const float*)d_in[20]; const float* g2b = (const float*)d_in[21];
  const float* g3w = (const float*)d_in[22]; const float* g3b = (const float*)d_in[23];
  const float* g4w = (const float*)d_in[24]; const float* g4b = (const float*)d_in[25];
  const float* f1w = (const float*)d_in[26]; const float* f1b = (const float*)d_in[27];
  const float* f2w = (const float*)d_in[28]; const float* f2b = (const float*)d_in[29];
  const float* f3w = (const float*)d_in[30]; const float* f3b = (const float*)d_in[31];
  const float* f4w = (const float*)d_in[32]; const float* f4b = (const float*)d_in[33];
  const float* ow  = (const float*)d_in[34]; const float* ob  = (const float*)d_in[35];
  float* out = (float*)d_out;
  (void)in_sizes; (void)n_in; (void)out_size;

  // ---------------- workspace sizing ----
  const size_t MB = 1024ull * 1024;
  const size_t PERSIST =
      2048ull * 640 * 2 + 3ull * 2048 * 2048 * 2 +
      4ull * 2048 * 4 +
      (128ull * 32 + 128 * 288 + 128 * 576 + 256 * 1152) * 2 +
      (128ull + 128 + 128 + 256) * 4 +
      2ull * 205 * 256 * 4 +
      2ull * 256 * 4 +
      3200ull * 256 * 2 +
      2048ull * BATCH * 4 +
      (2000ull + 1000 + 500 + 100) * BATCH * 4 +
      64ull * 256;

  auto need = [&](int CH) -> size_t {
    size_t gsz = (size_t)CH * 4096;
    size_t SA = gsz > 56 * MB ? gsz : 56 * MB;
    size_t SB = gsz > 30 * MB ? gsz : 30 * MB;
    size_t rsz = (size_t)CH * 1280;
    size_t SC = rsz > 14 * MB ? rsz : 14 * MB;
    return PERSIST + SA + SB + SC;
  };
  int CH = 2048;
  const int cands[3] = {16128, 8192, 4096};
  for (int ci = 0; ci < 3; ++ci)
    if (need(cands[ci]) <= ws_size) { CH = cands[ci]; break; }

  char* ws = (char*)d_ws;
  size_t off = 0;
  auto alloc = [&](size_t bytes) -> void* {
    void* p = ws + off;
    off += (bytes + 255) & ~(size_t)255;
    return p;
  };
  f16* wg1 = (f16*)alloc(2048ull * 640 * 2);
  f16* wg2 = (f16*)alloc(2048ull * 2048 * 2);
  f16* wg3 = (f16*)alloc(2048ull * 2048 * 2);
  f16* wg4 = (f16*)alloc(2048ull * 2048 * 2);
  float* bgp = (float*)alloc(4 * 2048 * 4);
  f16* wp1 = (f16*)alloc(128ull * 32 * 2);
  f16* wp2 = (f16*)alloc(128ull * 288 * 2);
  f16* wp3 = (f16*)alloc(128ull * 576 * 2);
  f16* wp4 = (f16*)alloc(256ull * 1152 * 2);
  float* bc1p = (float*)alloc(128 * 4);
  float* bc2p = (float*)alloc(128 * 4);
  float* bc3p = (float*)alloc(128 * 4);
  float* bc4p = (float*)alloc(256 * 4);
  float* psum = (float*)alloc(205ull * 256 * 4);
  float* psq  = (float*)alloc(205ull * 256 * 4);
  float* scl  = (float*)alloc(256 * 4);
  float* shf  = (float*)alloc(256 * 4);
  f16* y4 = (f16*)alloc(3200ull * 256 * 2);
  float* hsumT = (float*)alloc(2048ull * BATCH * 4);
  float* f1T = (float*)alloc(2000ull * BATCH * 4);
  float* f2T = (float*)alloc(1000ull * BATCH * 4);
  float* f3T = (float*)alloc(500ull * BATCH * 4);
  float* f4T = (float*)alloc(100ull * BATCH * 4);

  size_t gsz = (size_t)CH * 4096;
  size_t SA = gsz > 56 * MB ? gsz : 56 * MB;
  size_t SB = gsz > 30 * MB ? gsz : 30 * MB;
  size_t rsz = (size_t)CH * 1280;
  size_t SC = rsz > 14 * MB ? rsz : 14 * MB;
  char* regA = (char*)alloc(SA);
  char* regB = (char*)alloc(SB);
  char* regC = (char*)alloc(SC);

  f16* y1 = (f16*)regA;
  f16* A1 = (f16*)regB;
  f16* A2 = (f16*)regB;
  f16* y2 = (f16*)regC;
  f16* A3 = (f16*)regA;
  f16* y3 = (f16*)regB;
  f16* A4 = (f16*)(regB + 4 * MB);
  f16* hA = (f16*)regA;
  f16* hB = (f16*)regB;
  f16* relc = (f16*)regC;

  // ---- weight prep ----
  {
    long t1 = 2048L * 640;
    pad_w_f16<<<(int)((t1 + 255) / 256), 256, 0, stream>>>(g1w, wg1, 2000, 527, 640, t1);
    long t2 = 2048L * 2048;
    pad_w_f16<<<(int)((t2 + 255) / 256), 256, 0, stream>>>(g2w, wg2, 2000, 2000, 2048, t2);
    pad_w_f16<<<(int)((t2 + 255) / 256), 256, 0, stream>>>(g3w, wg3, 2000, 2000, 2048, t2);
    pad_w_f16<<<(int)((t2 + 255) / 256), 256, 0, stream>>>(g4w, wg4, 2000, 2000, 2048, t2);
    pad_bias<<<8, 256, 0, stream>>>(g1b, bgp + 0 * 2048, 2000, 2048);
    pad_bias<<<8, 256, 0, stream>>>(g2b, bgp + 1 * 2048, 2000, 2048);
    pad_bias<<<8, 256, 0, stream>>>(g3b, bgp + 2 * 2048, 2000, 2048);
    pad_bias<<<8, 256, 0, stream>>>(g4b, bgp + 3 * 2048, 2000, 2048);
    prep_convw<<<(128 * 32 + 255) / 256, 256, 0, stream>>>(c1w, wp1, 32, 3, 128, 32);
    prep_convw<<<(128 * 288 + 255) / 256, 256, 0, stream>>>(c2w, wp2, 64, 32, 128, 288);
    prep_convw<<<(128 * 576 + 255) / 256, 256, 0, stream>>>(c3w, wp3, 128, 64, 128, 576);
    prep_convw<<<(256 * 1152 + 255) / 256, 256, 0, stream>>>(c4w, wp4, 256, 128, 256, 1152);
    pad_bias<<<1, 256, 0, stream>>>(c1b, bc1p, 32, 128);
    pad_bias<<<1, 256, 0, stream>>>(c2b, bc2p, 64, 128);
    pad_bias<<<1, 256, 0, stream>>>(c3b, bc3p, 128, 128);
    pad_bias<<<1, 256, 0, stream>>>(c4b, bc4p, 256, 256);
  }

  // ---- conv stack: im2col + gemm(128^2) + BN ----
  im2col1<<<(204800 * 32 + 255) / 256, 256, 0, stream>>>(image, A1);
  gemm_f16<<<1600, 256, 0, stream>>>(A1, wp1, bc1p, y1, 204800, 128, 32);
  bn_part<<<200, 256, 0, stream>>>(y1, psum, psq, 204800, 128, 1024);
  bn_final<<<1, 256, 0, stream>>>(psum, psq, bn1g, bn1b, scl, shf, 200, 128, 32, 204800);
  bn_apply<<<(int)((204800L * 16 + 255) / 256), 256, 0, stream>>>(y1, scl, shf, 204800L * 16, 128);
  { long t = 51200L * 9 * 4;
    im2col_nhwc<<<(int)((t + 255) / 256), 256, 0, stream>>>(y1, A2, 40, 40, 20, 20, 128, 32, 288, t); }
  gemm_f16<<<400, 256, 0, stream>>>(A2, wp2, bc2p, y2, 51200, 128, 288);
  bn_part<<<50, 256, 0, stream>>>(y2, psum, psq, 51200, 128, 1024);
  bn_final<<<1, 256, 0, stream>>>(psum, psq, bn2g, bn2b, scl, shf, 50, 128, 64, 51200);
  bn_apply<<<(int)((51200L * 16 + 255) / 256), 256, 0, stream>>>(y2, scl, shf, 51200L * 16, 128);
  { long t = 12800L * 9 * 8;
    im2col_nhwc<<<(int)((t + 255) / 256), 256, 0, stream>>>(y2, A3, 20, 20, 10, 10, 128, 64, 576, t); }
  gemm_f16<<<100, 256, 0, stream>>>(A3, wp3, bc3p, y3, 12800, 128, 576);
  bn_part<<<13, 256, 0, stream>>>(y3, psum, psq, 12800, 128, 1024);
  bn_final<<<1, 256, 0, stream>>>(psum, psq, bn3g, bn3b, scl, shf, 13, 128, 128, 12800);
  bn_apply<<<(int)((12800L * 16 + 255) / 256), 256, 0, stream>>>(y3, scl, shf, 12800L * 16, 128);
  { long t = 3200L * 9 * 16;
    im2col_nhwc<<<(int)((t + 255) / 256), 256, 0, stream>>>(y3, A4, 10, 10, 5, 5, 128, 128, 1152, t); }
  gemm_f16<<<50, 256, 0, stream>>>(A4, wp4, bc4p, y4, 3200, 256, 1152);
  bn_part<<<4, 256, 0, stream>>>(y4, psum, psq, 3200, 256, 1024);
  bn_final<<<1, 256, 0, stream>>>(psum, psq, bn4g, bn4b, scl, shf, 4, 256, 256, 3200);
  bn_apply<<<(int)((3200L * 32 + 255) / 256), 256, 0, stream>>>(y4, scl, shf, 3200L * 32, 256);

  // ---- g-MLP (chunked, 256^2 8-phase GEMM) + pair sum ----
  hipMemsetAsync(hsumT, 0, 2048ull * BATCH * 4, stream);
  for (int start = 0; start < 80000; start += CH) {
    int M = 80000 - start;
    if (M > CH) M = CH;
    int Mp = (M + 255) & ~255;
    long tr = (long)Mp * 80;
    build_rel8<<<(int)((tr + 255) / 256), 256, 0, stream>>>(y4, questions, relc, start, Mp);
    int ng = (Mp / 256) * 8;
    gemm256<<<ng, 512, 0, stream>>>(relc, wg1, bgp + 0 * 2048, hA, Mp, 2048, 640);
    gemm256<<<ng, 512, 0, stream>>>(hA, wg2, bgp + 1 * 2048, hB, Mp, 2048, 2048);
    gemm256<<<ng, 512, 0, stream>>>(hB, wg3, bgp + 2 * 2048, hA, Mp, 2048, 2048);
    gemm256<<<ng, 512, 0, stream>>>(hA, wg4, bgp + 3 * 2048, hB, Mp, 2048, 2048);
    int gb0 = start / 625;
    int gb1 = (start + M - 1) / 625;
    dim3 sgrid(gb1 - gb0 + 1, 8);
    pair_sum_seg<<<sgrid, 256, 0, stream>>>(hB, hsumT, start, M, gb0);
  }

  // ---- f-MLP ----
  fc_t<<<2000, 128, 0, stream>>>(hsumT, f1w, f1b, f1T, 2000, 2000);
  fc_t<<<1000, 128, 0, stream>>>(f1T, f2w, f2b, f2T, 2000, 1000);
  fc_t<<<500, 128, 0, stream>>>(f2T, f3w, f3b, f3T, 1000, 500);
  fc_t<<<100, 128, 0, stream>>>(f3T, f4w, f4b, f4T, 500, 100);
  out_lsm<<<1, 128, 0, stream>>>(f4T, ow, ob, out);
}